// Round 12
// baseline (306.698 us; speedup 1.0000x reference)
//
#include <hip/hip_runtime.h>
#include <hip/hip_fp16.h>

#define N_NODES 50000
#define N_EDGES 800000
#define F_IN    128
#define HEADS   4
#define HID     64
#define LAT     64
#define N_EC    8
#define SLOPE   0.2f
#define NBUCKET 196                       // ceil(N_NODES/256); bucket = dst>>8
#define NABLK   196                       // ceil(N_EDGES/4096) coarse blocks
#define PLANE   ((size_t)N_NODES * 128)   // one head's xagg plane (bf16 elements)
#define PLANEU  ((size_t)N_NODES * 64)    // packed 2xbf16 units per plane

typedef __attribute__((ext_vector_type(8))) short bf16x8;   // 8 bf16 (4 VGPRs)
typedef __attribute__((ext_vector_type(4))) float f32x4;

__device__ __forceinline__ float lrelu(float x) { return x > 0.f ? x : SLOPE * x; }
__device__ __forceinline__ float4 operator+(float4 a, float4 b) { return make_float4(a.x+b.x, a.y+b.y, a.z+b.z, a.w+b.w); }
__device__ __forceinline__ float4 lrelu4(float4 a) { return make_float4(lrelu(a.x), lrelu(a.y), lrelu(a.z), lrelu(a.w)); }
__device__ __forceinline__ float4 exp4(float4 a) { return make_float4(__expf(a.x), __expf(a.y), __expf(a.z), __expf(a.w)); }

// bf16 helpers (manual, RNE)
__device__ __forceinline__ unsigned short f2bf(float f) {
    union { float f; unsigned u; } a; a.f = f;
    unsigned r = a.u + 0x7fffu + ((a.u >> 16) & 1u);
    return (unsigned short)(r >> 16);
}
__device__ __forceinline__ unsigned pack2bf(float x, float y) {
    return (unsigned)f2bf(x) | ((unsigned)f2bf(y) << 16);
}
__device__ __forceinline__ float2 bf2f2(unsigned u) {
    union { unsigned q; float f; } a, b;
    a.q = u << 16; b.q = u & 0xffff0000u;
    return make_float2(a.f, b.f);
}
// fp16 pair helpers (edge alphas)
__device__ __forceinline__ unsigned pack2h(float x, float y) {
    __half2 h = __floats2half2_rn(x, y);
    return *reinterpret_cast<unsigned*>(&h);
}
__device__ __forceinline__ float2 unpack2h(unsigned u) {
    __half2 h = *reinterpret_cast<__half2*>(&u);
    return __half22float2(h);
}

// ================= CSR build via 2-level MSD bucket sort (atomic-free global) =================
// A0: per-block histogram -> hist[block][bucket] (no memset, no global atomics)
__global__ __launch_bounds__(256) void bucket_count_kernel(const int* __restrict__ ei,
                                                           int* __restrict__ hist) {
    __shared__ int h[NBUCKET];
    int tid = threadIdx.x;
    for (int i = tid; i < NBUCKET; i += 256) h[i] = 0;
    __syncthreads();
    int beg = blockIdx.x * 4096;
    int end = min(beg + 4096, N_EDGES);
    for (int e = beg + tid; e < end; e += 256)
        atomicAdd(&h[ei[N_EDGES + e] >> 8], 1);
    __syncthreads();
    for (int i = tid; i < NBUCKET; i += 256)
        hist[blockIdx.x * NBUCKET + i] = h[i];
}

// A1: column-prefix hist -> basetab (in place) + bucket bases; row_start tail
__global__ __launch_bounds__(256) void scan_buckets_kernel(int* __restrict__ hist,
                                                           int* __restrict__ bbase,
                                                           int* __restrict__ row_start) {
    __shared__ int colsum[NBUCKET];
    int tid = threadIdx.x;
    if (tid < NBUCKET) {
        int acc = 0;
        for (int b = 0; b < NABLK; b++) {
            int idx = b * NBUCKET + tid;
            int v = hist[idx];
            hist[idx] = acc;          // exclusive prefix within bucket column
            acc += v;
        }
        colsum[tid] = acc;
    }
    __syncthreads();
    if (tid == 0) {
        int a = 0;
        for (int i = 0; i < NBUCKET; i++) { int t = colsum[i]; colsum[i] = a; a += t; }
        row_start[N_NODES] = N_EDGES;
    }
    __syncthreads();
    if (tid < NBUCKET) {
        int base = colsum[tid];
        bbase[tid] = base;
        for (int b = 0; b < NABLK; b++) hist[b * NBUCKET + tid] += base;
    }
    if (tid == 0) bbase[NBUCKET] = N_EDGES;
}

// A: coarse scatter — basetab gives each block its private output ranges (no global atomics)
// coarse record: word0 = s | (d_lo<<16), word1 = original edge id
__global__ __launch_bounds__(256) void coarse_scatter_kernel(const int* __restrict__ ei,
                                                             const int* __restrict__ basetab,
                                                             uint2* __restrict__ coarse) {
    __shared__ int h[NBUCKET];
    __shared__ int base[NBUCKET];
    int tid = threadIdx.x;
    for (int i = tid; i < NBUCKET; i += 256) h[i] = 0;
    __syncthreads();
    int beg = blockIdx.x * 4096;
    int w0_[16], o_[16], b_[16];
#pragma unroll
    for (int k = 0; k < 16; k++) {
        int e = beg + k * 256 + tid;
        b_[k] = -1;
        if (e < N_EDGES) {
            int s = ei[e], d = ei[N_EDGES + e];
            int bk = d >> 8;
            b_[k] = bk;
            w0_[k] = s | ((d & 255) << 16);
            o_[k] = e;
            atomicAdd(&h[bk], 1);
        }
    }
    __syncthreads();
    for (int i = tid; i < NBUCKET; i += 256) {
        base[i] = basetab[blockIdx.x * NBUCKET + i];
        h[i] = 0;
    }
    __syncthreads();
#pragma unroll
    for (int k = 0; k < 16; k++) {
        if (b_[k] >= 0) {
            int r = atomicAdd(&h[b_[k]], 1);
            coarse[base[b_[k]] + r] = make_uint2((unsigned)w0_[k], (unsigned)o_[k]);
        }
    }
}

// B: per-bucket fine sort; emits row_start + unified 16B edge records with fp16 conv1 alphas.
// exp without max-subtraction: logits are O(1) at this data scale; softmax shift-invariant.
__global__ __launch_bounds__(256) void fine_pass_kernel(const uint2* __restrict__ coarse,
                                                        const int* __restrict__ bbase,
                                                        const float4* __restrict__ as4,
                                                        const float4* __restrict__ ad4,
                                                        uint4* __restrict__ edges,
                                                        int* __restrict__ row_start) {
    int bucket = blockIdx.x;
    int tid = threadIdx.x;
    int lo = bbase[bucket], hi = bbase[bucket + 1];
    __shared__ int h[256];
    __shared__ int wsum[4];
    __shared__ int cur[256];
    h[tid] = 0;
    __syncthreads();
    for (int p = lo + tid; p < hi; p += 256)
        atomicAdd(&h[(coarse[p].x >> 16) & 0xff], 1);
    __syncthreads();
    int v = h[tid];
    int lane = tid & 63, w = tid >> 6;
    int incl = v;
#pragma unroll
    for (int off = 1; off < 64; off <<= 1) {
        int t = __shfl_up(incl, off, 64);
        if (lane >= off) incl += t;
    }
    if (lane == 63) wsum[w] = incl;
    __syncthreads();
    if (tid == 0) {
        int a = 0;
#pragma unroll
        for (int i = 0; i < 4; i++) { int t = wsum[i]; wsum[i] = a; a += t; }
    }
    __syncthreads();
    int excl = incl - v + wsum[w];
    int node = bucket * 256 + tid;
    if (node < N_NODES) row_start[node] = lo + excl;
    cur[tid] = lo + excl;
    __syncthreads();
    for (int p = lo + tid; p < hi; p += 256) {
        uint2 r = coarse[p];
        int dl = (r.x >> 16) & 0xff;
        int s = r.x & 0xffff;
        int d = bucket * 256 + dl;
        float4 al = exp4(lrelu4(as4[s] + ad4[d]));
        int pos = atomicAdd(&cur[dl], 1);
        edges[pos] = make_uint4((unsigned)(s | (d << 16)), r.y,
                                pack2h(al.x, al.y), pack2h(al.z, al.w));
    }
}

// ---------------- weights prep: watt + bf16 transposed weights (fused) ----------------
__global__ void wts_kernel(const float* __restrict__ W1, const float* __restrict__ W2,
                           const float* __restrict__ Wn, const float* __restrict__ We1,
                           const float* __restrict__ We2,
                           const float* __restrict__ as_, const float* __restrict__ ad_,
                           float* __restrict__ watt,
                           unsigned short* __restrict__ Bt1, unsigned short* __restrict__ Bt2,
                           unsigned short* __restrict__ Btd, unsigned short* __restrict__ Bte) {
    int idx = blockIdx.x * blockDim.x + threadIdx.x;
    if (idx < 256 * 128) {
        int n = idx >> 7, k = idx & 127;
        Bt1[idx] = f2bf(W1[k * 256 + n]);
    }
    if (idx < 64 * 256) {
        int n = idx >> 8, k = idx & 255;
        Bt2[idx] = f2bf(W2[k * 64 + n]);
    }
    if (idx < 256 * 64) {
        int n = idx >> 6, k = idx & 63;
        float v;
        if (n < 128) v = Wn[k * 128 + n];
        else {
            int nn = n - 128;
            v = (nn < 64) ? We1[k * 64 + nn] : We1[(64 + k) * 64 + (nn - 64)];
        }
        Btd[idx] = f2bf(v);
    }
    if (idx < 16 * 64) {
        int n = idx >> 6, k = idx & 63;
        Bte[idx] = (n < 8) ? f2bf(We2[k * 8 + n]) : (unsigned short)0;
    }
    if (idx < 128 * 8) {
        int k = idx >> 3, j = idx & 7;
        int h = j & 3;
        const float* av = (j < 4) ? as_ : ad_;
        float sum = 0.f;
        for (int c = 0; c < 64; c++) sum += W1[k * 256 + h * 64 + c] * av[h * 64 + c];
        watt[k * 8 + j] = sum;
    }
}

// ---------------- attention scalars from x (+ bf16 copy of x): wave per node ----------------
__global__ __launch_bounds__(256) void asad_kernel(const float* __restrict__ x,
                                                   const float* __restrict__ watt,
                                                   float4* __restrict__ as4,
                                                   float4* __restrict__ ad4,
                                                   unsigned* __restrict__ xb) {
    int wid = (blockIdx.x * blockDim.x + threadIdx.x) >> 6;
    int lane = threadIdx.x & 63;
    if (wid >= N_NODES) return;
    float2 xv = *reinterpret_cast<const float2*>(&x[(size_t)wid * 128 + lane * 2]);
    xb[(size_t)wid * 64 + lane] = pack2bf(xv.x, xv.y);
    float p[8];
    const float* w0 = &watt[(2 * lane) * 8];
    const float* w1 = &watt[(2 * lane + 1) * 8];
#pragma unroll
    for (int j = 0; j < 8; j++) p[j] = fmaf(xv.x, w0[j], xv.y * w1[j]);
#pragma unroll
    for (int off = 32; off; off >>= 1)
#pragma unroll
        for (int j = 0; j < 8; j++) p[j] += __shfl_xor(p[j], off, 64);
    if (lane == 0) {
        as4[wid] = make_float4(p[0], p[1], p[2], p[3]);
        ad4[wid] = make_float4(p[4], p[5], p[6], p[7]);
    }
}

// ---------------- conv1 accumulate: wave/node; 16B record scalar loads, 4-edge unroll ----------------
__global__ __launch_bounds__(256) void agg4x_acc_kernel(const unsigned* __restrict__ xb,
                                                        const float4* __restrict__ as4,
                                                        const float4* __restrict__ ad4,
                                                        const int* __restrict__ row_start,
                                                        const uint4* __restrict__ edges,
                                                        unsigned* __restrict__ xaggb) {
    int wid = (blockIdx.x * blockDim.x + threadIdx.x) >> 6;
    int lane = threadIdx.x & 63;
    if (wid >= N_NODES) return;
    int beg = __builtin_amdgcn_readfirstlane(row_start[wid]);
    int end = __builtin_amdgcn_readfirstlane(row_start[wid + 1]);
    float4 adn = ad4[wid];
    float4 e_self = exp4(lrelu4(as4[wid] + adn));
    float4 den = e_self;
    float2 xv = bf2f2(xb[(size_t)wid * 64 + lane]);
    float2 acc0 = make_float2(e_self.x * xv.x, e_self.x * xv.y);
    float2 acc1 = make_float2(e_self.y * xv.x, e_self.y * xv.y);
    float2 acc2 = make_float2(e_self.z * xv.x, e_self.z * xv.y);
    float2 acc3 = make_float2(e_self.w * xv.x, e_self.w * xv.y);

#define EDGE_ACC(rec, vu)                                                     \
    {                                                                         \
        float2 a01 = unpack2h((rec).z);                                       \
        float2 a23 = unpack2h((rec).w);                                       \
        float2 vv = bf2f2(vu);                                                \
        acc0.x = fmaf(a01.x, vv.x, acc0.x); acc0.y = fmaf(a01.x, vv.y, acc0.y); \
        acc1.x = fmaf(a01.y, vv.x, acc1.x); acc1.y = fmaf(a01.y, vv.y, acc1.y); \
        acc2.x = fmaf(a23.x, vv.x, acc2.x); acc2.y = fmaf(a23.x, vv.y, acc2.y); \
        acc3.x = fmaf(a23.y, vv.x, acc3.x); acc3.y = fmaf(a23.y, vv.y, acc3.y); \
        den.x += a01.x; den.y += a01.y; den.z += a23.x; den.w += a23.y;       \
    }

    int j = beg;
    for (; j + 3 < end; j += 4) {
        uint4 r0 = edges[j], r1 = edges[j + 1], r2 = edges[j + 2], r3 = edges[j + 3];
        unsigned v0 = xb[(size_t)(r0.x & 0xffff) * 64 + lane];
        unsigned v1 = xb[(size_t)(r1.x & 0xffff) * 64 + lane];
        unsigned v2 = xb[(size_t)(r2.x & 0xffff) * 64 + lane];
        unsigned v3 = xb[(size_t)(r3.x & 0xffff) * 64 + lane];
        EDGE_ACC(r0, v0);
        EDGE_ACC(r1, v1);
        EDGE_ACC(r2, v2);
        EDGE_ACC(r3, v3);
    }
    for (; j < end; j++) {
        uint4 r = edges[j];
        unsigned v = xb[(size_t)(r.x & 0xffff) * 64 + lane];
        EDGE_ACC(r, v);
    }
#undef EDGE_ACC
    float i0 = 1.f / (den.x + 1e-16f);
    float i1 = 1.f / (den.y + 1e-16f);
    float i2 = 1.f / (den.z + 1e-16f);
    float i3 = 1.f / (den.w + 1e-16f);
    size_t base = (size_t)wid * 64 + lane;
    xaggb[0 * PLANEU + base] = pack2bf(acc0.x * i0, acc0.y * i0);
    xaggb[1 * PLANEU + base] = pack2bf(acc1.x * i1, acc1.y * i1);
    xaggb[2 * PLANEU + base] = pack2bf(acc2.x * i2, acc2.y * i2);
    xaggb[3 * PLANEU + base] = pack2bf(acc3.x * i3, acc3.y * i3);
}

// ================= MFMA GEMMs (16x16x32 bf16, LDS-free) =================

// conv1: per-head (blockIdx.y): A plane, cols [y*64, y*64+64); bias+relu, bf16 out
template <int K>
__global__ __launch_bounds__(256) void mfma_gemm1_kernel(const unsigned short* __restrict__ A,
                                                         int lda, long aPlane,
                                                         const unsigned short* __restrict__ Bt,
                                                         const float* __restrict__ bias,
                                                         unsigned short* __restrict__ C, int ldc,
                                                         int M) {
    int tid = threadIdx.x;
    int w = tid >> 6, l = tid & 63;
    int bcol = blockIdx.y * 64;
    A += (size_t)blockIdx.y * aPlane;
    int row_a = blockIdx.x * 64 + w * 16 + (l & 15);
    int kq = (l >> 4) * 8;
    bool aval = row_a < M;
    const unsigned short* Arow = A + (size_t)row_a * lda;
    f32x4 acc[4] = {};
#pragma unroll
    for (int kb = 0; kb < K / 32; kb++) {
        int k0 = kb * 32 + kq;
        bf16x8 a = {};
        if (aval) a = *reinterpret_cast<const bf16x8*>(&Arow[k0]);
#pragma unroll
        for (int nb = 0; nb < 4; nb++) {
            bf16x8 b = *reinterpret_cast<const bf16x8*>(
                &Bt[(size_t)(bcol + nb * 16 + (l & 15)) * K + k0]);
            acc[nb] = __builtin_amdgcn_mfma_f32_16x16x32_bf16(a, b, acc[nb], 0, 0, 0);
        }
    }
    int orow = blockIdx.x * 64 + w * 16 + (l >> 4) * 4;
#pragma unroll
    for (int nb = 0; nb < 4; nb++) {
        int col = bcol + nb * 16 + (l & 15);
        float bb = bias[col];
#pragma unroll
        for (int r = 0; r < 4; r++) {
            int row = orow + r;
            if (row < M) C[(size_t)row * ldc + col] = f2bf(fmaxf(acc[nb][r] + bb, 0.f));
        }
    }
}

// conv2 (K=256, N=64): bf16 H2 out + fused per-row attention scalars (from fp32 acc)
__global__ __launch_bounds__(256) void mfma_gemm2_kernel(const unsigned short* __restrict__ A,
                                                         const unsigned short* __restrict__ Bt,
                                                         const float* __restrict__ att_src,
                                                         const float* __restrict__ att_dst,
                                                         unsigned short* __restrict__ h2b,
                                                         float* __restrict__ as_,
                                                         float* __restrict__ ad_, int M) {
    int tid = threadIdx.x;
    int w = tid >> 6, l = tid & 63;
    int row_a = blockIdx.x * 64 + w * 16 + (l & 15);
    int kq = (l >> 4) * 8;
    bool aval = row_a < M;
    const unsigned short* Arow = A + (size_t)row_a * 256;
    f32x4 acc[4] = {};
#pragma unroll
    for (int kb = 0; kb < 8; kb++) {
        int k0 = kb * 32 + kq;
        bf16x8 a = {};
        if (aval) a = *reinterpret_cast<const bf16x8*>(&Arow[k0]);
#pragma unroll
        for (int nb = 0; nb < 4; nb++) {
            bf16x8 b = *reinterpret_cast<const bf16x8*>(
                &Bt[(size_t)(nb * 16 + (l & 15)) * 256 + k0]);
            acc[nb] = __builtin_amdgcn_mfma_f32_16x16x32_bf16(a, b, acc[nb], 0, 0, 0);
        }
    }
    int orow = blockIdx.x * 64 + w * 16 + (l >> 4) * 4;
    float ps[4] = {}, pd[4] = {};
#pragma unroll
    for (int nb = 0; nb < 4; nb++) {
        int col = nb * 16 + (l & 15);
        float s = att_src[col], dd = att_dst[col];
#pragma unroll
        for (int r = 0; r < 4; r++) {
            float v = acc[nb][r];
            ps[r] = fmaf(v, s, ps[r]);
            pd[r] = fmaf(v, dd, pd[r]);
            int row = orow + r;
            if (row < M) h2b[(size_t)row * 64 + col] = f2bf(v);
        }
    }
#pragma unroll
    for (int off = 1; off <= 8; off <<= 1)
#pragma unroll
        for (int r = 0; r < 4; r++) {
            ps[r] += __shfl_xor(ps[r], off, 64);
            pd[r] += __shfl_xor(pd[r], off, 64);
        }
    if ((l & 15) == 0) {
#pragma unroll
        for (int r = 0; r < 4; r++) {
            int row = orow + r;
            if (row < M) { as_[row] = ps[r]; ad_[row] = pd[r]; }
        }
    }
}

// decode (K=64, N=256): cols<128 -> recon_x fp32 (+bn); cols>=128 -> PQb bf16
__global__ __launch_bounds__(256) void mfma_gemm_decode_kernel(const unsigned short* __restrict__ zb,
                                                               const unsigned short* __restrict__ Btd,
                                                               const float* __restrict__ bn,
                                                               float* __restrict__ recon_x,
                                                               unsigned short* __restrict__ PQb,
                                                               int M) {
    int tid = threadIdx.x;
    int w = tid >> 6, l = tid & 63;
    int bcol = blockIdx.y * 64;
    int row_a = blockIdx.x * 64 + w * 16 + (l & 15);
    int kq = (l >> 4) * 8;
    bool aval = row_a < M;
    const unsigned short* Arow = zb + (size_t)row_a * 64;
    f32x4 acc[4] = {};
#pragma unroll
    for (int kb = 0; kb < 2; kb++) {
        int k0 = kb * 32 + kq;
        bf16x8 a = {};
        if (aval) a = *reinterpret_cast<const bf16x8*>(&Arow[k0]);
#pragma unroll
        for (int nb = 0; nb < 4; nb++) {
            bf16x8 b = *reinterpret_cast<const bf16x8*>(
                &Btd[(size_t)(bcol + nb * 16 + (l & 15)) * 64 + k0]);
            acc[nb] = __builtin_amdgcn_mfma_f32_16x16x32_bf16(a, b, acc[nb], 0, 0, 0);
        }
    }
    int orow = blockIdx.x * 64 + w * 16 + (l >> 4) * 4;
#pragma unroll
    for (int nb = 0; nb < 4; nb++) {
        int col = bcol + nb * 16 + (l & 15);
        if (col < 128) {
            float bb = bn[col];
#pragma unroll
            for (int r = 0; r < 4; r++) {
                int row = orow + r;
                if (row < M) recon_x[(size_t)row * 128 + col] = acc[nb][r] + bb;
            }
        } else {
#pragma unroll
            for (int r = 0; r < 4; r++) {
                int row = orow + r;
                if (row < M) PQb[(size_t)row * 128 + (col - 128)] = f2bf(acc[nb][r]);
            }
        }
    }
}

// ---------------- conv2 per-edge alpha (CSR order) ----------------
__global__ void alpha1_kernel(const uint4* __restrict__ edges,
                              const float* __restrict__ as_, const float* __restrict__ ad_,
                              float* __restrict__ alpha1) {
    int p = blockIdx.x * blockDim.x + threadIdx.x;
    if (p < N_EDGES) {
        unsigned w0 = edges[p].x;
        alpha1[p] = __expf(lrelu(as_[w0 & 0xffff] + ad_[w0 >> 16]));
    }
}

// ---------------- conv2 accumulate: wave/node, 2 edges/iter, bf16 z out ----------------
__global__ __launch_bounds__(256) void agg1_acc_kernel(const unsigned* __restrict__ h2b,
                                                       const float* __restrict__ as_,
                                                       const float* __restrict__ ad_,
                                                       const int* __restrict__ row_start,
                                                       const uint4* __restrict__ edges,
                                                       const float* __restrict__ alpha1,
                                                       const float* __restrict__ bias,
                                                       unsigned* __restrict__ zb) {
    int wid = (blockIdx.x * blockDim.x + threadIdx.x) >> 6;
    int lane = threadIdx.x & 63;
    if (wid >= N_NODES) return;
    int g = lane >> 5;
    int c = lane & 31;
    int beg = __builtin_amdgcn_readfirstlane(row_start[wid]);
    int end = __builtin_amdgcn_readfirstlane(row_start[wid + 1]);
    float adn = ad_[wid];
    float e_self = __expf(lrelu(as_[wid] + adn));
    float den = (g == 0) ? e_self : 0.f;
    float2 hv = bf2f2(h2b[(size_t)wid * 32 + c]);
    float2 acc = (g == 0) ? make_float2(e_self * hv.x, e_self * hv.y)
                          : make_float2(0.f, 0.f);
    for (int j = beg; j < end; j += 2) {
        float a0 = alpha1[j];
        int s0 = edges[j].x & 0xffff;
        float a1 = 0.f;
        int s1 = s0;
        if (j + 1 < end) { a1 = alpha1[j + 1]; s1 = edges[j + 1].x & 0xffff; }
        float e = g ? a1 : a0;
        int s = g ? s1 : s0;
        float2 v = bf2f2(h2b[(size_t)s * 32 + c]);
        acc.x = fmaf(e, v.x, acc.x);
        acc.y = fmaf(e, v.y, acc.y);
        den += e;
    }
    den += __shfl_xor(den, 32, 64);
    acc.x += __shfl_xor(acc.x, 32, 64);
    acc.y += __shfl_xor(acc.y, 32, 64);
    if (g == 0) {
        float inv = 1.f / (den + 1e-16f);
        float2 bb = *reinterpret_cast<const float2*>(&bias[2 * c]);
        zb[(size_t)wid * 32 + c] = pack2bf(acc.x * inv + bb.x, acc.y * inv + bb.y);
    }
}

// ---------------- MFMA edge decode: 16 edges/wave, 16B records ----------------
#define ED_BLOCKS 2048
__device__ __forceinline__ bf16x8 make_t(uint4 up, uint4 uq, float4 ba, float4 bb) {
    float2 p0 = bf2f2(up.x), p1 = bf2f2(up.y), p2 = bf2f2(up.z), p3 = bf2f2(up.w);
    float2 q0 = bf2f2(uq.x), q1 = bf2f2(uq.y), q2 = bf2f2(uq.z), q3 = bf2f2(uq.w);
    unsigned r0 = pack2bf(fmaxf(p0.x + q0.x + ba.x, 0.f), fmaxf(p0.y + q0.y + ba.y, 0.f));
    unsigned r1 = pack2bf(fmaxf(p1.x + q1.x + ba.z, 0.f), fmaxf(p1.y + q1.y + ba.w, 0.f));
    unsigned r2 = pack2bf(fmaxf(p2.x + q2.x + bb.x, 0.f), fmaxf(p2.y + q2.y + bb.y, 0.f));
    unsigned r3 = pack2bf(fmaxf(p3.x + q3.x + bb.z, 0.f), fmaxf(p3.y + q3.y + bb.w, 0.f));
    union { uint4 u; bf16x8 v; } c;
    c.u = make_uint4(r0, r1, r2, r3);
    return c.v;
}

__global__ __launch_bounds__(256) void mfma_edge_decode_kernel(const unsigned short* __restrict__ PQb,
                                                               const uint4* __restrict__ edges,
                                                               const float* __restrict__ be1,
                                                               const unsigned short* __restrict__ Bte,
                                                               const float* __restrict__ be2,
                                                               float* __restrict__ out) {
    int tid = threadIdx.x;
    int l = tid & 63;
    int col = l & 15;
    int kq = (l >> 4) * 8;
    bf16x8 b0 = *reinterpret_cast<const bf16x8*>(&Bte[col * 64 + kq]);
    bf16x8 b1 = *reinterpret_cast<const bf16x8*>(&Bte[col * 64 + 32 + kq]);
    float4 ba0 = *reinterpret_cast<const float4*>(&be1[kq]);
    float4 bb0 = *reinterpret_cast<const float4*>(&be1[kq + 4]);
    float4 ba1 = *reinterpret_cast<const float4*>(&be1[32 + kq]);
    float4 bb1 = *reinterpret_cast<const float4*>(&be1[32 + kq + 4]);
    float bout = (col < 8) ? be2[col] : 0.f;
    int rbase = (l >> 4) * 4;

    int wgid = (blockIdx.x * blockDim.x + tid) >> 6;
    const int nwaves = ED_BLOCKS * 4;
    const int ngroups = N_EDGES / 16;
    for (int g = wgid; g < ngroups; g += nwaves) {
        int base = g * 16;
        unsigned ex = edges[base + col].x;
        int s = ex & 0xffff, d = ex >> 16;
        const unsigned short* Pr = &PQb[(size_t)s * 128];
        const unsigned short* Qr = &PQb[(size_t)d * 128 + 64];
        uint4 up0 = *reinterpret_cast<const uint4*>(&Pr[kq]);
        uint4 uq0 = *reinterpret_cast<const uint4*>(&Qr[kq]);
        uint4 up1 = *reinterpret_cast<const uint4*>(&Pr[32 + kq]);
        uint4 uq1 = *reinterpret_cast<const uint4*>(&Qr[32 + kq]);
        bf16x8 a0 = make_t(up0, uq0, ba0, bb0);
        bf16x8 a1 = make_t(up1, uq1, ba1, bb1);
        f32x4 acc = {};
        acc = __builtin_amdgcn_mfma_f32_16x16x32_bf16(a0, b0, acc, 0, 0, 0);
        acc = __builtin_amdgcn_mfma_f32_16x16x32_bf16(a1, b1, acc, 0, 0, 0);
        if (col < 8) {
#pragma unroll
            for (int r = 0; r < 4; r++) {
                int o = edges[base + rbase + r].y;
                out[(size_t)o * 8 + col] = acc[r] + bout;
            }
        }
    }
}

extern "C" void kernel_launch(void* const* d_in, const int* in_sizes, int n_in,
                              void* d_out, int out_size, void* d_ws, size_t ws_size,
                              hipStream_t stream) {
    const float* x        = (const float*)d_in[0];
    const int*   ei       = (const int*)d_in[1];
    const float* W1       = (const float*)d_in[2];
    const float* att_src1 = (const float*)d_in[3];
    const float* att_dst1 = (const float*)d_in[4];
    const float* b1       = (const float*)d_in[5];
    const float* W2       = (const float*)d_in[6];
    const float* att_src2 = (const float*)d_in[7];
    const float* att_dst2 = (const float*)d_in[8];
    const float* b2       = (const float*)d_in[9];
    const float* Wn       = (const float*)d_in[10];
    const float* bn       = (const float*)d_in[11];
    const float* We1      = (const float*)d_in[12];
    const float* be1      = (const float*)d_in[13];
    const float* We2      = (const float*)d_in[14];
    const float* be2      = (const float*)d_in[15];

    char* ws = (char*)d_ws;
    size_t off = 0;
    auto alloc = [&](size_t bytes) {
        void* p = ws + off;
        off += (bytes + 255) & ~(size_t)255;
        return p;
    };
    int*   hist      = (int*)alloc((size_t)NABLK * NBUCKET * 4);              // 154 KB
    int*   bbase     = (int*)alloc((size_t)(NBUCKET + 1) * 4);
    int*   row_start = (int*)alloc((size_t)(N_NODES + 1) * 4);
    uint2* coarse    = (uint2*)alloc((size_t)N_EDGES * 8);                    // 6.4 MB
    uint4* edges     = (uint4*)alloc((size_t)N_EDGES * 16);                   // 12.8 MB
    float* watt      = (float*)alloc((size_t)128 * 8 * 4);
    float* as1       = (float*)alloc((size_t)N_NODES * 4 * 4);
    float* ad1       = (float*)alloc((size_t)N_NODES * 4 * 4);
    unsigned* xb     = (unsigned*)alloc((size_t)N_NODES * 64 * 4);            // 12.8 MB bf16
    unsigned* xaggb  = (unsigned*)alloc((size_t)4 * PLANEU * 4);              // 25.6 MB bf16
    unsigned short* houtb = (unsigned short*)alloc((size_t)N_NODES * 256 * 2); // 25.6 MB bf16
    unsigned* h2b    = (unsigned*)alloc((size_t)N_NODES * 32 * 4);            // 6.4 MB bf16
    float* as2       = (float*)alloc((size_t)N_NODES * 4);
    float* ad2       = (float*)alloc((size_t)N_NODES * 4);
    float* alpha1    = (float*)alloc((size_t)N_EDGES * 4);                    // 3.2 MB
    unsigned* zb     = (unsigned*)alloc((size_t)N_NODES * 32 * 4);            // 6.4 MB bf16
    unsigned short* PQb = (unsigned short*)alloc((size_t)N_NODES * 128 * 2);  // 12.8 MB
    unsigned short* Bt1 = (unsigned short*)alloc((size_t)256 * 128 * 2);
    unsigned short* Bt2 = (unsigned short*)alloc((size_t)64 * 256 * 2);
    unsigned short* Btd = (unsigned short*)alloc((size_t)256 * 64 * 2);
    unsigned short* Bte = (unsigned short*)alloc((size_t)16 * 64 * 2);

    float* recon_x = (float*)d_out;
    float* recon_e = (float*)d_out + (size_t)N_NODES * F_IN;

    // CSR build: atomic-free histogram/scan/scatter + fused-alpha fine pass
    bucket_count_kernel<<<NABLK, 256, 0, stream>>>(ei, hist);
    scan_buckets_kernel<<<1, 256, 0, stream>>>(hist, bbase, row_start);
    wts_kernel<<<128, 256, 0, stream>>>(W1, W2, Wn, We1, We2, att_src1, att_dst1,
                                        watt, Bt1, Bt2, Btd, Bte);
    asad_kernel<<<(N_NODES * 64 + 255) / 256, 256, 0, stream>>>(x, watt, (float4*)as1,
                                                                (float4*)ad1, xb);
    coarse_scatter_kernel<<<NABLK, 256, 0, stream>>>(ei, hist, coarse);
    fine_pass_kernel<<<NBUCKET, 256, 0, stream>>>(coarse, bbase, (const float4*)as1,
                                                  (const float4*)ad1, edges, row_start);

    // conv1 accumulate + per-head MFMA GEMM applies W1 (bf16 out)
    agg4x_acc_kernel<<<(N_NODES * 64 + 255) / 256, 256, 0, stream>>>(
        xb, (const float4*)as1, (const float4*)ad1, row_start, edges, xaggb);
    dim3 gc1((N_NODES + 63) / 64, 4);
    mfma_gemm1_kernel<128><<<gc1, 256, 0, stream>>>(
        (const unsigned short*)xaggb, 128, (long)PLANE, Bt1, b1, houtb, 256, N_NODES);

    // conv2: MFMA GEMM with fused att-scalar epilogue, then alpha + accumulate
    mfma_gemm2_kernel<<<(N_NODES + 63) / 64, 256, 0, stream>>>(
        houtb, Bt2, att_src2, att_dst2, (unsigned short*)h2b, as2, ad2, N_NODES);
    alpha1_kernel<<<(N_EDGES + 255) / 256, 256, 0, stream>>>(edges, as2, ad2, alpha1);
    agg1_acc_kernel<<<(N_NODES * 64 + 255) / 256, 256, 0, stream>>>(
        h2b, as2, ad2, row_start, edges, alpha1, b2, zb);

    // fused decode MFMA GEMM: recon_x (fp32) + PQ (bf16) in one pass over zb
    dim3 gdec((N_NODES + 63) / 64, 4);
    mfma_gemm_decode_kernel<<<gdec, 256, 0, stream>>>(
        (const unsigned short*)zb, Btd, bn, recon_x, PQb, N_NODES);

    // MFMA edge decode (CSR order, 16B records)
    mfma_edge_decode_kernel<<<ED_BLOCKS, 256, 0, stream>>>(PQb, edges, be1, Bte, be2, recon_e);
}

// Round 13
// 294.317 us; speedup vs baseline: 1.0421x; 1.0421x over previous
//
#include <hip/hip_runtime.h>
#include <hip/hip_fp16.h>

#define N_NODES 50000
#define N_EDGES 800000
#define F_IN    128
#define HEADS   4
#define HID     64
#define LAT     64
#define N_EC    8
#define SLOPE   0.2f
#define NBUCKET 196                       // ceil(N_NODES/256); bucket = dst>>8
#define NABLK   196                       // ceil(N_EDGES/4096) coarse blocks
#define PLANE   ((size_t)N_NODES * 128)   // one head's xagg plane (bf16 elements)
#define PLANEU  ((size_t)N_NODES * 64)    // packed 2xbf16 units per plane

typedef __attribute__((ext_vector_type(8))) short bf16x8;   // 8 bf16 (4 VGPRs)
typedef __attribute__((ext_vector_type(4))) float f32x4;

__device__ __forceinline__ float lrelu(float x) { return x > 0.f ? x : SLOPE * x; }
__device__ __forceinline__ float4 operator+(float4 a, float4 b) { return make_float4(a.x+b.x, a.y+b.y, a.z+b.z, a.w+b.w); }
__device__ __forceinline__ float4 lrelu4(float4 a) { return make_float4(lrelu(a.x), lrelu(a.y), lrelu(a.z), lrelu(a.w)); }
__device__ __forceinline__ float4 exp4(float4 a) { return make_float4(__expf(a.x), __expf(a.y), __expf(a.z), __expf(a.w)); }

// bf16 helpers (manual, RNE)
__device__ __forceinline__ unsigned short f2bf(float f) {
    union { float f; unsigned u; } a; a.f = f;
    unsigned r = a.u + 0x7fffu + ((a.u >> 16) & 1u);
    return (unsigned short)(r >> 16);
}
__device__ __forceinline__ unsigned pack2bf(float x, float y) {
    return (unsigned)f2bf(x) | ((unsigned)f2bf(y) << 16);
}
__device__ __forceinline__ float2 bf2f2(unsigned u) {
    union { unsigned q; float f; } a, b;
    a.q = u << 16; b.q = u & 0xffff0000u;
    return make_float2(a.f, b.f);
}
// fp16 pair helpers (edge alphas)
__device__ __forceinline__ unsigned pack2h(float x, float y) {
    __half2 h = __floats2half2_rn(x, y);
    return *reinterpret_cast<unsigned*>(&h);
}
__device__ __forceinline__ float2 unpack2h(unsigned u) {
    __half2 h = *reinterpret_cast<__half2*>(&u);
    return __half22float2(h);
}

// ================= CSR build via 2-level MSD bucket sort (atomic-free global) =================
__global__ __launch_bounds__(256) void bucket_count_kernel(const int* __restrict__ ei,
                                                           int* __restrict__ hist) {
    __shared__ int h[NBUCKET];
    int tid = threadIdx.x;
    for (int i = tid; i < NBUCKET; i += 256) h[i] = 0;
    __syncthreads();
    int beg = blockIdx.x * 4096;
    int end = min(beg + 4096, N_EDGES);
    for (int e = beg + tid; e < end; e += 256)
        atomicAdd(&h[ei[N_EDGES + e] >> 8], 1);
    __syncthreads();
    for (int i = tid; i < NBUCKET; i += 256)
        hist[blockIdx.x * NBUCKET + i] = h[i];
}

__global__ __launch_bounds__(256) void scan_buckets_kernel(int* __restrict__ hist,
                                                           int* __restrict__ bbase,
                                                           int* __restrict__ row_start) {
    __shared__ int colsum[NBUCKET];
    int tid = threadIdx.x;
    if (tid < NBUCKET) {
        int acc = 0;
        for (int b = 0; b < NABLK; b++) {
            int idx = b * NBUCKET + tid;
            int v = hist[idx];
            hist[idx] = acc;
            acc += v;
        }
        colsum[tid] = acc;
    }
    __syncthreads();
    if (tid == 0) {
        int a = 0;
        for (int i = 0; i < NBUCKET; i++) { int t = colsum[i]; colsum[i] = a; a += t; }
        row_start[N_NODES] = N_EDGES;
    }
    __syncthreads();
    if (tid < NBUCKET) {
        int base = colsum[tid];
        bbase[tid] = base;
        for (int b = 0; b < NABLK; b++) hist[b * NBUCKET + tid] += base;
    }
    if (tid == 0) bbase[NBUCKET] = N_EDGES;
}

__global__ __launch_bounds__(256) void coarse_scatter_kernel(const int* __restrict__ ei,
                                                             const int* __restrict__ basetab,
                                                             uint2* __restrict__ coarse) {
    __shared__ int h[NBUCKET];
    __shared__ int base[NBUCKET];
    int tid = threadIdx.x;
    for (int i = tid; i < NBUCKET; i += 256) h[i] = 0;
    __syncthreads();
    int beg = blockIdx.x * 4096;
    int w0_[16], o_[16], b_[16];
#pragma unroll
    for (int k = 0; k < 16; k++) {
        int e = beg + k * 256 + tid;
        b_[k] = -1;
        if (e < N_EDGES) {
            int s = ei[e], d = ei[N_EDGES + e];
            int bk = d >> 8;
            b_[k] = bk;
            w0_[k] = s | ((d & 255) << 16);
            o_[k] = e;
            atomicAdd(&h[bk], 1);
        }
    }
    __syncthreads();
    for (int i = tid; i < NBUCKET; i += 256) {
        base[i] = basetab[blockIdx.x * NBUCKET + i];
        h[i] = 0;
    }
    __syncthreads();
#pragma unroll
    for (int k = 0; k < 16; k++) {
        if (b_[k] >= 0) {
            int r = atomicAdd(&h[b_[k]], 1);
            coarse[base[b_[k]] + r] = make_uint2((unsigned)w0_[k], (unsigned)o_[k]);
        }
    }
}

// B: per-bucket fine sort; emits row_start + unified 16B edge records with fp16 conv1 alphas.
__global__ __launch_bounds__(256) void fine_pass_kernel(const uint2* __restrict__ coarse,
                                                        const int* __restrict__ bbase,
                                                        const float4* __restrict__ as4,
                                                        const float4* __restrict__ ad4,
                                                        uint4* __restrict__ edges,
                                                        int* __restrict__ row_start) {
    int bucket = blockIdx.x;
    int tid = threadIdx.x;
    int lo = bbase[bucket], hi = bbase[bucket + 1];
    __shared__ int h[256];
    __shared__ int wsum[4];
    __shared__ int cur[256];
    h[tid] = 0;
    __syncthreads();
    for (int p = lo + tid; p < hi; p += 256)
        atomicAdd(&h[(coarse[p].x >> 16) & 0xff], 1);
    __syncthreads();
    int v = h[tid];
    int lane = tid & 63, w = tid >> 6;
    int incl = v;
#pragma unroll
    for (int off = 1; off < 64; off <<= 1) {
        int t = __shfl_up(incl, off, 64);
        if (lane >= off) incl += t;
    }
    if (lane == 63) wsum[w] = incl;
    __syncthreads();
    if (tid == 0) {
        int a = 0;
#pragma unroll
        for (int i = 0; i < 4; i++) { int t = wsum[i]; wsum[i] = a; a += t; }
    }
    __syncthreads();
    int excl = incl - v + wsum[w];
    int node = bucket * 256 + tid;
    if (node < N_NODES) row_start[node] = lo + excl;
    cur[tid] = lo + excl;
    __syncthreads();
    for (int p = lo + tid; p < hi; p += 256) {
        uint2 r = coarse[p];
        int dl = (r.x >> 16) & 0xff;
        int s = r.x & 0xffff;
        int d = bucket * 256 + dl;
        float4 al = exp4(lrelu4(as4[s] + ad4[d]));
        int pos = atomicAdd(&cur[dl], 1);
        edges[pos] = make_uint4((unsigned)(s | (d << 16)), r.y,
                                pack2h(al.x, al.y), pack2h(al.z, al.w));
    }
}

// ---------------- weights prep: watt + bf16 transposed weights (fused) ----------------
__global__ void wts_kernel(const float* __restrict__ W1, const float* __restrict__ W2,
                           const float* __restrict__ Wn, const float* __restrict__ We1,
                           const float* __restrict__ We2,
                           const float* __restrict__ as_, const float* __restrict__ ad_,
                           float* __restrict__ watt,
                           unsigned short* __restrict__ Bt1, unsigned short* __restrict__ Bt2,
                           unsigned short* __restrict__ Btd, unsigned short* __restrict__ Bte) {
    int idx = blockIdx.x * blockDim.x + threadIdx.x;
    if (idx < 256 * 128) {
        int n = idx >> 7, k = idx & 127;
        Bt1[idx] = f2bf(W1[k * 256 + n]);
    }
    if (idx < 64 * 256) {
        int n = idx >> 8, k = idx & 255;
        Bt2[idx] = f2bf(W2[k * 64 + n]);
    }
    if (idx < 256 * 64) {
        int n = idx >> 6, k = idx & 63;
        float v;
        if (n < 128) v = Wn[k * 128 + n];
        else {
            int nn = n - 128;
            v = (nn < 64) ? We1[k * 64 + nn] : We1[(64 + k) * 64 + (nn - 64)];
        }
        Btd[idx] = f2bf(v);
    }
    if (idx < 16 * 64) {
        int n = idx >> 6, k = idx & 63;
        Bte[idx] = (n < 8) ? f2bf(We2[k * 8 + n]) : (unsigned short)0;
    }
    if (idx < 128 * 8) {
        int k = idx >> 3, j = idx & 7;
        int h = j & 3;
        const float* av = (j < 4) ? as_ : ad_;
        float sum = 0.f;
        for (int c = 0; c < 64; c++) sum += W1[k * 256 + h * 64 + c] * av[h * 64 + c];
        watt[k * 8 + j] = sum;
    }
}

// ---------------- attention scalars from x (+ bf16 copy of x): wave per node ----------------
__global__ __launch_bounds__(256) void asad_kernel(const float* __restrict__ x,
                                                   const float* __restrict__ watt,
                                                   float4* __restrict__ as4,
                                                   float4* __restrict__ ad4,
                                                   unsigned* __restrict__ xb) {
    int wid = (blockIdx.x * blockDim.x + threadIdx.x) >> 6;
    int lane = threadIdx.x & 63;
    if (wid >= N_NODES) return;
    float2 xv = *reinterpret_cast<const float2*>(&x[(size_t)wid * 128 + lane * 2]);
    xb[(size_t)wid * 64 + lane] = pack2bf(xv.x, xv.y);
    float p[8];
    const float* w0 = &watt[(2 * lane) * 8];
    const float* w1 = &watt[(2 * lane + 1) * 8];
#pragma unroll
    for (int j = 0; j < 8; j++) p[j] = fmaf(xv.x, w0[j], xv.y * w1[j]);
#pragma unroll
    for (int off = 32; off; off >>= 1)
#pragma unroll
        for (int j = 0; j < 8; j++) p[j] += __shfl_xor(p[j], off, 64);
    if (lane == 0) {
        as4[wid] = make_float4(p[0], p[1], p[2], p[3]);
        ad4[wid] = make_float4(p[4], p[5], p[6], p[7]);
    }
}

// ---------------- conv1 accumulate: wave/node; 16B record scalar loads, 4-edge unroll ----------------
__global__ __launch_bounds__(256) void agg4x_acc_kernel(const unsigned* __restrict__ xb,
                                                        const float4* __restrict__ as4,
                                                        const float4* __restrict__ ad4,
                                                        const int* __restrict__ row_start,
                                                        const uint4* __restrict__ edges,
                                                        unsigned* __restrict__ xaggb) {
    int wid = (blockIdx.x * blockDim.x + threadIdx.x) >> 6;
    int lane = threadIdx.x & 63;
    if (wid >= N_NODES) return;
    int beg = __builtin_amdgcn_readfirstlane(row_start[wid]);
    int end = __builtin_amdgcn_readfirstlane(row_start[wid + 1]);
    float4 adn = ad4[wid];
    float4 e_self = exp4(lrelu4(as4[wid] + adn));
    float4 den = e_self;
    float2 xv = bf2f2(xb[(size_t)wid * 64 + lane]);
    float2 acc0 = make_float2(e_self.x * xv.x, e_self.x * xv.y);
    float2 acc1 = make_float2(e_self.y * xv.x, e_self.y * xv.y);
    float2 acc2 = make_float2(e_self.z * xv.x, e_self.z * xv.y);
    float2 acc3 = make_float2(e_self.w * xv.x, e_self.w * xv.y);

#define EDGE_ACC(rec, vu)                                                     \
    {                                                                         \
        float2 a01 = unpack2h((rec).z);                                       \
        float2 a23 = unpack2h((rec).w);                                       \
        float2 vv = bf2f2(vu);                                                \
        acc0.x = fmaf(a01.x, vv.x, acc0.x); acc0.y = fmaf(a01.x, vv.y, acc0.y); \
        acc1.x = fmaf(a01.y, vv.x, acc1.x); acc1.y = fmaf(a01.y, vv.y, acc1.y); \
        acc2.x = fmaf(a23.x, vv.x, acc2.x); acc2.y = fmaf(a23.x, vv.y, acc2.y); \
        acc3.x = fmaf(a23.y, vv.x, acc3.x); acc3.y = fmaf(a23.y, vv.y, acc3.y); \
        den.x += a01.x; den.y += a01.y; den.z += a23.x; den.w += a23.y;       \
    }

    int j = beg;
    for (; j + 3 < end; j += 4) {
        uint4 r0 = edges[j], r1 = edges[j + 1], r2 = edges[j + 2], r3 = edges[j + 3];
        unsigned v0 = xb[(size_t)(r0.x & 0xffff) * 64 + lane];
        unsigned v1 = xb[(size_t)(r1.x & 0xffff) * 64 + lane];
        unsigned v2 = xb[(size_t)(r2.x & 0xffff) * 64 + lane];
        unsigned v3 = xb[(size_t)(r3.x & 0xffff) * 64 + lane];
        EDGE_ACC(r0, v0);
        EDGE_ACC(r1, v1);
        EDGE_ACC(r2, v2);
        EDGE_ACC(r3, v3);
    }
    for (; j < end; j++) {
        uint4 r = edges[j];
        unsigned v = xb[(size_t)(r.x & 0xffff) * 64 + lane];
        EDGE_ACC(r, v);
    }
#undef EDGE_ACC
    float i0 = 1.f / (den.x + 1e-16f);
    float i1 = 1.f / (den.y + 1e-16f);
    float i2 = 1.f / (den.z + 1e-16f);
    float i3 = 1.f / (den.w + 1e-16f);
    size_t base = (size_t)wid * 64 + lane;
    xaggb[0 * PLANEU + base] = pack2bf(acc0.x * i0, acc0.y * i0);
    xaggb[1 * PLANEU + base] = pack2bf(acc1.x * i1, acc1.y * i1);
    xaggb[2 * PLANEU + base] = pack2bf(acc2.x * i2, acc2.y * i2);
    xaggb[3 * PLANEU + base] = pack2bf(acc3.x * i3, acc3.y * i3);
}

// ================= MFMA GEMMs (16x16x32 bf16, LDS-free) =================

template <int K>
__global__ __launch_bounds__(256) void mfma_gemm1_kernel(const unsigned short* __restrict__ A,
                                                         int lda, long aPlane,
                                                         const unsigned short* __restrict__ Bt,
                                                         const float* __restrict__ bias,
                                                         unsigned short* __restrict__ C, int ldc,
                                                         int M) {
    int tid = threadIdx.x;
    int w = tid >> 6, l = tid & 63;
    int bcol = blockIdx.y * 64;
    A += (size_t)blockIdx.y * aPlane;
    int row_a = blockIdx.x * 64 + w * 16 + (l & 15);
    int kq = (l >> 4) * 8;
    bool aval = row_a < M;
    const unsigned short* Arow = A + (size_t)row_a * lda;
    f32x4 acc[4] = {};
#pragma unroll
    for (int kb = 0; kb < K / 32; kb++) {
        int k0 = kb * 32 + kq;
        bf16x8 a = {};
        if (aval) a = *reinterpret_cast<const bf16x8*>(&Arow[k0]);
#pragma unroll
        for (int nb = 0; nb < 4; nb++) {
            bf16x8 b = *reinterpret_cast<const bf16x8*>(
                &Bt[(size_t)(bcol + nb * 16 + (l & 15)) * K + k0]);
            acc[nb] = __builtin_amdgcn_mfma_f32_16x16x32_bf16(a, b, acc[nb], 0, 0, 0);
        }
    }
    int orow = blockIdx.x * 64 + w * 16 + (l >> 4) * 4;
#pragma unroll
    for (int nb = 0; nb < 4; nb++) {
        int col = bcol + nb * 16 + (l & 15);
        float bb = bias[col];
#pragma unroll
        for (int r = 0; r < 4; r++) {
            int row = orow + r;
            if (row < M) C[(size_t)row * ldc + col] = f2bf(fmaxf(acc[nb][r] + bb, 0.f));
        }
    }
}

__global__ __launch_bounds__(256) void mfma_gemm2_kernel(const unsigned short* __restrict__ A,
                                                         const unsigned short* __restrict__ Bt,
                                                         const float* __restrict__ att_src,
                                                         const float* __restrict__ att_dst,
                                                         unsigned short* __restrict__ h2b,
                                                         float* __restrict__ as_,
                                                         float* __restrict__ ad_, int M) {
    int tid = threadIdx.x;
    int w = tid >> 6, l = tid & 63;
    int row_a = blockIdx.x * 64 + w * 16 + (l & 15);
    int kq = (l >> 4) * 8;
    bool aval = row_a < M;
    const unsigned short* Arow = A + (size_t)row_a * 256;
    f32x4 acc[4] = {};
#pragma unroll
    for (int kb = 0; kb < 8; kb++) {
        int k0 = kb * 32 + kq;
        bf16x8 a = {};
        if (aval) a = *reinterpret_cast<const bf16x8*>(&Arow[k0]);
#pragma unroll
        for (int nb = 0; nb < 4; nb++) {
            bf16x8 b = *reinterpret_cast<const bf16x8*>(
                &Bt[(size_t)(nb * 16 + (l & 15)) * 256 + k0]);
            acc[nb] = __builtin_amdgcn_mfma_f32_16x16x32_bf16(a, b, acc[nb], 0, 0, 0);
        }
    }
    int orow = blockIdx.x * 64 + w * 16 + (l >> 4) * 4;
    float ps[4] = {}, pd[4] = {};
#pragma unroll
    for (int nb = 0; nb < 4; nb++) {
        int col = nb * 16 + (l & 15);
        float s = att_src[col], dd = att_dst[col];
#pragma unroll
        for (int r = 0; r < 4; r++) {
            float v = acc[nb][r];
            ps[r] = fmaf(v, s, ps[r]);
            pd[r] = fmaf(v, dd, pd[r]);
            int row = orow + r;
            if (row < M) h2b[(size_t)row * 64 + col] = f2bf(v);
        }
    }
#pragma unroll
    for (int off = 1; off <= 8; off <<= 1)
#pragma unroll
        for (int r = 0; r < 4; r++) {
            ps[r] += __shfl_xor(ps[r], off, 64);
            pd[r] += __shfl_xor(pd[r], off, 64);
        }
    if ((l & 15) == 0) {
#pragma unroll
        for (int r = 0; r < 4; r++) {
            int row = orow + r;
            if (row < M) { as_[row] = ps[r]; ad_[row] = pd[r]; }
        }
    }
}

__global__ __launch_bounds__(256) void mfma_gemm_decode_kernel(const unsigned short* __restrict__ zb,
                                                               const unsigned short* __restrict__ Btd,
                                                               const float* __restrict__ bn,
                                                               float* __restrict__ recon_x,
                                                               unsigned short* __restrict__ PQb,
                                                               int M) {
    int tid = threadIdx.x;
    int w = tid >> 6, l = tid & 63;
    int bcol = blockIdx.y * 64;
    int row_a = blockIdx.x * 64 + w * 16 + (l & 15);
    int kq = (l >> 4) * 8;
    bool aval = row_a < M;
    const unsigned short* Arow = zb + (size_t)row_a * 64;
    f32x4 acc[4] = {};
#pragma unroll
    for (int kb = 0; kb < 2; kb++) {
        int k0 = kb * 32 + kq;
        bf16x8 a = {};
        if (aval) a = *reinterpret_cast<const bf16x8*>(&Arow[k0]);
#pragma unroll
        for (int nb = 0; nb < 4; nb++) {
            bf16x8 b = *reinterpret_cast<const bf16x8*>(
                &Btd[(size_t)(bcol + nb * 16 + (l & 15)) * 64 + k0]);
            acc[nb] = __builtin_amdgcn_mfma_f32_16x16x32_bf16(a, b, acc[nb], 0, 0, 0);
        }
    }
    int orow = blockIdx.x * 64 + w * 16 + (l >> 4) * 4;
#pragma unroll
    for (int nb = 0; nb < 4; nb++) {
        int col = bcol + nb * 16 + (l & 15);
        if (col < 128) {
            float bb = bn[col];
#pragma unroll
            for (int r = 0; r < 4; r++) {
                int row = orow + r;
                if (row < M) recon_x[(size_t)row * 128 + col] = acc[nb][r] + bb;
            }
        } else {
#pragma unroll
            for (int r = 0; r < 4; r++) {
                int row = orow + r;
                if (row < M) PQb[(size_t)row * 128 + (col - 128)] = f2bf(acc[nb][r]);
            }
        }
    }
}

// ---------------- conv2 per-edge alpha: packed {alpha_bits, src} records ----------------
__global__ void alpha1_kernel(const uint4* __restrict__ edges,
                              const float* __restrict__ as_, const float* __restrict__ ad_,
                              uint2* __restrict__ av) {
    int p = blockIdx.x * blockDim.x + threadIdx.x;
    if (p < N_EDGES) {
        unsigned w0 = edges[p].x;
        int s = w0 & 0xffff;
        float a = __expf(lrelu(as_[s] + ad_[w0 >> 16]));
        av[p] = make_uint2(__float_as_uint(a), (unsigned)s);
    }
}

// ---------------- conv2 accumulate: 4 edge-slots x 16 lanes, 4 edges/iter ----------------
__global__ __launch_bounds__(256) void agg1_acc_kernel(const uint2* __restrict__ h2b2,
                                                       const float* __restrict__ as_,
                                                       const float* __restrict__ ad_,
                                                       const int* __restrict__ row_start,
                                                       const uint2* __restrict__ av,
                                                       const float* __restrict__ bias,
                                                       unsigned* __restrict__ zb) {
    int wid = (blockIdx.x * blockDim.x + threadIdx.x) >> 6;
    int lane = threadIdx.x & 63;
    if (wid >= N_NODES) return;
    int g = lane >> 4;        // edge slot 0..3
    int c16 = lane & 15;      // channel quad -> channels [c16*4, c16*4+4)
    int beg = __builtin_amdgcn_readfirstlane(row_start[wid]);
    int end = __builtin_amdgcn_readfirstlane(row_start[wid + 1]);
    float adn = ad_[wid];
    float e_self = __expf(lrelu(as_[wid] + adn));
    float den = (g == 0) ? e_self : 0.f;
    uint2 hv = h2b2[(size_t)wid * 16 + c16];
    float2 h01 = bf2f2(hv.x), h23 = bf2f2(hv.y);
    float4 acc = (g == 0) ? make_float4(e_self * h01.x, e_self * h01.y,
                                        e_self * h23.x, e_self * h23.y)
                          : make_float4(0.f, 0.f, 0.f, 0.f);
    for (int j = beg + g; j < end; j += 4) {
        uint2 rec = av[j];                       // broadcast within slot (L1)
        float e = __uint_as_float(rec.x);
        uint2 v = h2b2[(size_t)rec.y * 16 + c16];
        float2 v01 = bf2f2(v.x), v23 = bf2f2(v.y);
        acc.x = fmaf(e, v01.x, acc.x);
        acc.y = fmaf(e, v01.y, acc.y);
        acc.z = fmaf(e, v23.x, acc.z);
        acc.w = fmaf(e, v23.y, acc.w);
        den += e;
    }
#pragma unroll
    for (int off = 16; off <= 32; off <<= 1) {
        den += __shfl_xor(den, off, 64);
        acc.x += __shfl_xor(acc.x, off, 64);
        acc.y += __shfl_xor(acc.y, off, 64);
        acc.z += __shfl_xor(acc.z, off, 64);
        acc.w += __shfl_xor(acc.w, off, 64);
    }
    if (g == 0) {
        float inv = 1.f / (den + 1e-16f);
        const float4 bb = *reinterpret_cast<const float4*>(&bias[c16 * 4]);
        uint2 o;
        o.x = pack2bf(acc.x * inv + bb.x, acc.y * inv + bb.y);
        o.y = pack2bf(acc.z * inv + bb.z, acc.w * inv + bb.w);
        *reinterpret_cast<uint2*>(&zb[(size_t)wid * 32 + c16 * 2]) = o;
    }
}

// ---------------- MFMA edge decode: 16 edges/wave, 16B records ----------------
#define ED_BLOCKS 2048
__device__ __forceinline__ bf16x8 make_t(uint4 up, uint4 uq, float4 ba, float4 bb) {
    float2 p0 = bf2f2(up.x), p1 = bf2f2(up.y), p2 = bf2f2(up.z), p3 = bf2f2(up.w);
    float2 q0 = bf2f2(uq.x), q1 = bf2f2(uq.y), q2 = bf2f2(uq.z), q3 = bf2f2(uq.w);
    unsigned r0 = pack2bf(fmaxf(p0.x + q0.x + ba.x, 0.f), fmaxf(p0.y + q0.y + ba.y, 0.f));
    unsigned r1 = pack2bf(fmaxf(p1.x + q1.x + ba.z, 0.f), fmaxf(p1.y + q1.y + ba.w, 0.f));
    unsigned r2 = pack2bf(fmaxf(p2.x + q2.x + bb.x, 0.f), fmaxf(p2.y + q2.y + bb.y, 0.f));
    unsigned r3 = pack2bf(fmaxf(p3.x + q3.x + bb.z, 0.f), fmaxf(p3.y + q3.y + bb.w, 0.f));
    union { uint4 u; bf16x8 v; } c;
    c.u = make_uint4(r0, r1, r2, r3);
    return c.v;
}

__global__ __launch_bounds__(256) void mfma_edge_decode_kernel(const unsigned short* __restrict__ PQb,
                                                               const uint4* __restrict__ edges,
                                                               const float* __restrict__ be1,
                                                               const unsigned short* __restrict__ Bte,
                                                               const float* __restrict__ be2,
                                                               float* __restrict__ out) {
    int tid = threadIdx.x;
    int l = tid & 63;
    int col = l & 15;
    int kq = (l >> 4) * 8;
    bf16x8 b0 = *reinterpret_cast<const bf16x8*>(&Bte[col * 64 + kq]);
    bf16x8 b1 = *reinterpret_cast<const bf16x8*>(&Bte[col * 64 + 32 + kq]);
    float4 ba0 = *reinterpret_cast<const float4*>(&be1[kq]);
    float4 bb0 = *reinterpret_cast<const float4*>(&be1[kq + 4]);
    float4 ba1 = *reinterpret_cast<const float4*>(&be1[32 + kq]);
    float4 bb1 = *reinterpret_cast<const float4*>(&be1[32 + kq + 4]);
    float bout = (col < 8) ? be2[col] : 0.f;
    int rbase = (l >> 4) * 4;

    int wgid = (blockIdx.x * blockDim.x + tid) >> 6;
    const int nwaves = ED_BLOCKS * 4;
    const int ngroups = N_EDGES / 16;
    for (int g = wgid; g < ngroups; g += nwaves) {
        int base = g * 16;
        unsigned ex = edges[base + col].x;
        int s = ex & 0xffff, d = ex >> 16;
        const unsigned short* Pr = &PQb[(size_t)s * 128];
        const unsigned short* Qr = &PQb[(size_t)d * 128 + 64];
        uint4 up0 = *reinterpret_cast<const uint4*>(&Pr[kq]);
        uint4 uq0 = *reinterpret_cast<const uint4*>(&Qr[kq]);
        uint4 up1 = *reinterpret_cast<const uint4*>(&Pr[32 + kq]);
        uint4 uq1 = *reinterpret_cast<const uint4*>(&Qr[32 + kq]);
        bf16x8 a0 = make_t(up0, uq0, ba0, bb0);
        bf16x8 a1 = make_t(up1, uq1, ba1, bb1);
        f32x4 acc = {};
        acc = __builtin_amdgcn_mfma_f32_16x16x32_bf16(a0, b0, acc, 0, 0, 0);
        acc = __builtin_amdgcn_mfma_f32_16x16x32_bf16(a1, b1, acc, 0, 0, 0);
        if (col < 8) {
#pragma unroll
            for (int r = 0; r < 4; r++) {
                int o = edges[base + rbase + r].y;
                out[(size_t)o * 8 + col] = acc[r] + bout;
            }
        }
    }
}

extern "C" void kernel_launch(void* const* d_in, const int* in_sizes, int n_in,
                              void* d_out, int out_size, void* d_ws, size_t ws_size,
                              hipStream_t stream) {
    const float* x        = (const float*)d_in[0];
    const int*   ei       = (const int*)d_in[1];
    const float* W1       = (const float*)d_in[2];
    const float* att_src1 = (const float*)d_in[3];
    const float* att_dst1 = (const float*)d_in[4];
    const float* b1       = (const float*)d_in[5];
    const float* W2       = (const float*)d_in[6];
    const float* att_src2 = (const float*)d_in[7];
    const float* att_dst2 = (const float*)d_in[8];
    const float* b2       = (const float*)d_in[9];
    const float* Wn       = (const float*)d_in[10];
    const float* bn       = (const float*)d_in[11];
    const float* We1      = (const float*)d_in[12];
    const float* be1      = (const float*)d_in[13];
    const float* We2      = (const float*)d_in[14];
    const float* be2      = (const float*)d_in[15];

    char* ws = (char*)d_ws;
    size_t off = 0;
    auto alloc = [&](size_t bytes) {
        void* p = ws + off;
        off += (bytes + 255) & ~(size_t)255;
        return p;
    };
    int*   hist      = (int*)alloc((size_t)NABLK * NBUCKET * 4);
    int*   bbase     = (int*)alloc((size_t)(NBUCKET + 1) * 4);
    int*   row_start = (int*)alloc((size_t)(N_NODES + 1) * 4);
    uint2* coarse    = (uint2*)alloc((size_t)N_EDGES * 8);
    uint4* edges     = (uint4*)alloc((size_t)N_EDGES * 16);
    float* watt      = (float*)alloc((size_t)128 * 8 * 4);
    float* as1       = (float*)alloc((size_t)N_NODES * 4 * 4);
    float* ad1       = (float*)alloc((size_t)N_NODES * 4 * 4);
    unsigned* xb     = (unsigned*)alloc((size_t)N_NODES * 64 * 4);
    unsigned* xaggb  = (unsigned*)alloc((size_t)4 * PLANEU * 4);
    unsigned short* houtb = (unsigned short*)alloc((size_t)N_NODES * 256 * 2);
    unsigned* h2b    = (unsigned*)alloc((size_t)N_NODES * 32 * 4);
    float* as2       = (float*)alloc((size_t)N_NODES * 4);
    float* ad2       = (float*)alloc((size_t)N_NODES * 4);
    uint2* av        = (uint2*)alloc((size_t)N_EDGES * 8);
    unsigned* zb     = (unsigned*)alloc((size_t)N_NODES * 32 * 4);
    unsigned short* PQb = (unsigned short*)alloc((size_t)N_NODES * 128 * 2);
    unsigned short* Bt1 = (unsigned short*)alloc((size_t)256 * 128 * 2);
    unsigned short* Bt2 = (unsigned short*)alloc((size_t)64 * 256 * 2);
    unsigned short* Btd = (unsigned short*)alloc((size_t)256 * 64 * 2);
    unsigned short* Bte = (unsigned short*)alloc((size_t)16 * 64 * 2);

    float* recon_x = (float*)d_out;
    float* recon_e = (float*)d_out + (size_t)N_NODES * F_IN;

    // CSR build: atomic-free histogram/scan/scatter + fused-alpha fine pass
    bucket_count_kernel<<<NABLK, 256, 0, stream>>>(ei, hist);
    scan_buckets_kernel<<<1, 256, 0, stream>>>(hist, bbase, row_start);
    wts_kernel<<<128, 256, 0, stream>>>(W1, W2, Wn, We1, We2, att_src1, att_dst1,
                                        watt, Bt1, Bt2, Btd, Bte);
    asad_kernel<<<(N_NODES * 64 + 255) / 256, 256, 0, stream>>>(x, watt, (float4*)as1,
                                                                (float4*)ad1, xb);
    coarse_scatter_kernel<<<NABLK, 256, 0, stream>>>(ei, hist, coarse);
    fine_pass_kernel<<<NBUCKET, 256, 0, stream>>>(coarse, bbase, (const float4*)as1,
                                                  (const float4*)ad1, edges, row_start);

    // conv1 accumulate + per-head MFMA GEMM applies W1 (bf16 out)
    agg4x_acc_kernel<<<(N_NODES * 64 + 255) / 256, 256, 0, stream>>>(
        xb, (const float4*)as1, (const float4*)ad1, row_start, edges, xaggb);
    dim3 gc1((N_NODES + 63) / 64, 4);
    mfma_gemm1_kernel<128><<<gc1, 256, 0, stream>>>(
        (const unsigned short*)xaggb, 128, (long)PLANE, Bt1, b1, houtb, 256, N_NODES);

    // conv2: MFMA GEMM with fused att-scalar epilogue, then alpha + accumulate
    mfma_gemm2_kernel<<<(N_NODES + 63) / 64, 256, 0, stream>>>(
        houtb, Bt2, att_src2, att_dst2, (unsigned short*)h2b, as2, ad2, N_NODES);
    alpha1_kernel<<<(N_EDGES + 255) / 256, 256, 0, stream>>>(edges, as2, ad2, av);
    agg1_acc_kernel<<<(N_NODES * 64 + 255) / 256, 256, 0, stream>>>(
        (const uint2*)h2b, as2, ad2, row_start, av, b2, zb);

    // fused decode MFMA GEMM: recon_x (fp32) + PQ (bf16) in one pass over zb
    dim3 gdec((N_NODES + 63) / 64, 4);
    mfma_gemm_decode_kernel<<<gdec, 256, 0, stream>>>(
        (const unsigned short*)zb, Btd, bn, recon_x, PQb, N_NODES);

    // MFMA edge decode (CSR order, 16B records)
    mfma_edge_decode_kernel<<<ED_BLOCKS, 256, 0, stream>>>(PQb, edges, be1, Bte, be2, recon_e);
}

// Round 14
// 293.702 us; speedup vs baseline: 1.0443x; 1.0021x over previous
//
#include <hip/hip_runtime.h>
#include <hip/hip_fp16.h>

#define N_NODES 50000
#define N_EDGES 800000
#define F_IN    128
#define HEADS   4
#define HID     64
#define LAT     64
#define N_EC    8
#define SLOPE   0.2f
#define NBUCKET 196                       // ceil(N_NODES/256); bucket = dst>>8
#define NABLK   196                       // ceil(N_EDGES/4096) coarse blocks
#define PLANE   ((size_t)N_NODES * 128)   // one head's xagg plane (bf16 elements)
#define PLANEU  ((size_t)N_NODES * 64)    // packed 2xbf16 units per plane

typedef __attribute__((ext_vector_type(8))) short bf16x8;   // 8 bf16 (4 VGPRs)
typedef __attribute__((ext_vector_type(4))) float f32x4;
typedef __attribute__((ext_vector_type(2))) float f32x2;    // maps to v_pk_*_f32

__device__ __forceinline__ float lrelu(float x) { return x > 0.f ? x : SLOPE * x; }
__device__ __forceinline__ float4 operator+(float4 a, float4 b) { return make_float4(a.x+b.x, a.y+b.y, a.z+b.z, a.w+b.w); }
__device__ __forceinline__ float4 lrelu4(float4 a) { return make_float4(lrelu(a.x), lrelu(a.y), lrelu(a.z), lrelu(a.w)); }
__device__ __forceinline__ float4 exp4(float4 a) { return make_float4(__expf(a.x), __expf(a.y), __expf(a.z), __expf(a.w)); }

// bf16 helpers (manual, RNE)
__device__ __forceinline__ unsigned short f2bf(float f) {
    union { float f; unsigned u; } a; a.f = f;
    unsigned r = a.u + 0x7fffu + ((a.u >> 16) & 1u);
    return (unsigned short)(r >> 16);
}
__device__ __forceinline__ unsigned pack2bf(float x, float y) {
    return (unsigned)f2bf(x) | ((unsigned)f2bf(y) << 16);
}
__device__ __forceinline__ float2 bf2f2(unsigned u) {
    union { unsigned q; float f; } a, b;
    a.q = u << 16; b.q = u & 0xffff0000u;
    return make_float2(a.f, b.f);
}
__device__ __forceinline__ f32x2 bf2v2(unsigned u) {
    union { unsigned q; float f; } a, b;
    a.q = u << 16; b.q = u & 0xffff0000u;
    return (f32x2){a.f, b.f};
}
// fp16 pair helpers (edge alphas)
__device__ __forceinline__ unsigned pack2h(float x, float y) {
    __half2 h = __floats2half2_rn(x, y);
    return *reinterpret_cast<unsigned*>(&h);
}
__device__ __forceinline__ float2 unpack2h(unsigned u) {
    __half2 h = *reinterpret_cast<__half2*>(&u);
    return __half22float2(h);
}
__device__ __forceinline__ f32x2 unpack2hv(unsigned u) {
    __half2 h = *reinterpret_cast<__half2*>(&u);
    float2 f = __half22float2(h);
    return (f32x2){f.x, f.y};
}

// ================= CSR build via 2-level MSD bucket sort (atomic-free global) =================
__global__ __launch_bounds__(256) void bucket_count_kernel(const int* __restrict__ ei,
                                                           int* __restrict__ hist) {
    __shared__ int h[NBUCKET];
    int tid = threadIdx.x;
    for (int i = tid; i < NBUCKET; i += 256) h[i] = 0;
    __syncthreads();
    int beg = blockIdx.x * 4096;
    int end = min(beg + 4096, N_EDGES);
    for (int e = beg + tid; e < end; e += 256)
        atomicAdd(&h[ei[N_EDGES + e] >> 8], 1);
    __syncthreads();
    for (int i = tid; i < NBUCKET; i += 256)
        hist[blockIdx.x * NBUCKET + i] = h[i];
}

__global__ __launch_bounds__(256) void scan_buckets_kernel(int* __restrict__ hist,
                                                           int* __restrict__ bbase,
                                                           int* __restrict__ row_start) {
    __shared__ int colsum[NBUCKET];
    int tid = threadIdx.x;
    if (tid < NBUCKET) {
        int acc = 0;
        for (int b = 0; b < NABLK; b++) {
            int idx = b * NBUCKET + tid;
            int v = hist[idx];
            hist[idx] = acc;
            acc += v;
        }
        colsum[tid] = acc;
    }
    __syncthreads();
    if (tid == 0) {
        int a = 0;
        for (int i = 0; i < NBUCKET; i++) { int t = colsum[i]; colsum[i] = a; a += t; }
        row_start[N_NODES] = N_EDGES;
    }
    __syncthreads();
    if (tid < NBUCKET) {
        int base = colsum[tid];
        bbase[tid] = base;
        for (int b = 0; b < NABLK; b++) hist[b * NBUCKET + tid] += base;
    }
    if (tid == 0) bbase[NBUCKET] = N_EDGES;
}

__global__ __launch_bounds__(256) void coarse_scatter_kernel(const int* __restrict__ ei,
                                                             const int* __restrict__ basetab,
                                                             uint2* __restrict__ coarse) {
    __shared__ int h[NBUCKET];
    __shared__ int base[NBUCKET];
    int tid = threadIdx.x;
    for (int i = tid; i < NBUCKET; i += 256) h[i] = 0;
    __syncthreads();
    int beg = blockIdx.x * 4096;
    int w0_[16], o_[16], b_[16];
#pragma unroll
    for (int k = 0; k < 16; k++) {
        int e = beg + k * 256 + tid;
        b_[k] = -1;
        if (e < N_EDGES) {
            int s = ei[e], d = ei[N_EDGES + e];
            int bk = d >> 8;
            b_[k] = bk;
            w0_[k] = s | ((d & 255) << 16);
            o_[k] = e;
            atomicAdd(&h[bk], 1);
        }
    }
    __syncthreads();
    for (int i = tid; i < NBUCKET; i += 256) {
        base[i] = basetab[blockIdx.x * NBUCKET + i];
        h[i] = 0;
    }
    __syncthreads();
#pragma unroll
    for (int k = 0; k < 16; k++) {
        if (b_[k] >= 0) {
            int r = atomicAdd(&h[b_[k]], 1);
            coarse[base[b_[k]] + r] = make_uint2((unsigned)w0_[k], (unsigned)o_[k]);
        }
    }
}

// B: per-bucket fine sort; emits row_start + unified 16B edge records with fp16 conv1 alphas.
__global__ __launch_bounds__(256) void fine_pass_kernel(const uint2* __restrict__ coarse,
                                                        const int* __restrict__ bbase,
                                                        const float4* __restrict__ as4,
                                                        const float4* __restrict__ ad4,
                                                        uint4* __restrict__ edges,
                                                        int* __restrict__ row_start) {
    int bucket = blockIdx.x;
    int tid = threadIdx.x;
    int lo = bbase[bucket], hi = bbase[bucket + 1];
    __shared__ int h[256];
    __shared__ int wsum[4];
    __shared__ int cur[256];
    h[tid] = 0;
    __syncthreads();
    for (int p = lo + tid; p < hi; p += 256)
        atomicAdd(&h[(coarse[p].x >> 16) & 0xff], 1);
    __syncthreads();
    int v = h[tid];
    int lane = tid & 63, w = tid >> 6;
    int incl = v;
#pragma unroll
    for (int off = 1; off < 64; off <<= 1) {
        int t = __shfl_up(incl, off, 64);
        if (lane >= off) incl += t;
    }
    if (lane == 63) wsum[w] = incl;
    __syncthreads();
    if (tid == 0) {
        int a = 0;
#pragma unroll
        for (int i = 0; i < 4; i++) { int t = wsum[i]; wsum[i] = a; a += t; }
    }
    __syncthreads();
    int excl = incl - v + wsum[w];
    int node = bucket * 256 + tid;
    if (node < N_NODES) row_start[node] = lo + excl;
    cur[tid] = lo + excl;
    __syncthreads();
    for (int p = lo + tid; p < hi; p += 256) {
        uint2 r = coarse[p];
        int dl = (r.x >> 16) & 0xff;
        int s = r.x & 0xffff;
        int d = bucket * 256 + dl;
        float4 al = exp4(lrelu4(as4[s] + ad4[d]));
        int pos = atomicAdd(&cur[dl], 1);
        edges[pos] = make_uint4((unsigned)(s | (d << 16)), r.y,
                                pack2h(al.x, al.y), pack2h(al.z, al.w));
    }
}

// ---------------- weights prep: watt + bf16 transposed weights (fused) ----------------
__global__ void wts_kernel(const float* __restrict__ W1, const float* __restrict__ W2,
                           const float* __restrict__ Wn, const float* __restrict__ We1,
                           const float* __restrict__ We2,
                           const float* __restrict__ as_, const float* __restrict__ ad_,
                           float* __restrict__ watt,
                           unsigned short* __restrict__ Bt1, unsigned short* __restrict__ Bt2,
                           unsigned short* __restrict__ Btd, unsigned short* __restrict__ Bte) {
    int idx = blockIdx.x * blockDim.x + threadIdx.x;
    if (idx < 256 * 128) {
        int n = idx >> 7, k = idx & 127;
        Bt1[idx] = f2bf(W1[k * 256 + n]);
    }
    if (idx < 64 * 256) {
        int n = idx >> 8, k = idx & 255;
        Bt2[idx] = f2bf(W2[k * 64 + n]);
    }
    if (idx < 256 * 64) {
        int n = idx >> 6, k = idx & 63;
        float v;
        if (n < 128) v = Wn[k * 128 + n];
        else {
            int nn = n - 128;
            v = (nn < 64) ? We1[k * 64 + nn] : We1[(64 + k) * 64 + (nn - 64)];
        }
        Btd[idx] = f2bf(v);
    }
    if (idx < 16 * 64) {
        int n = idx >> 6, k = idx & 63;
        Bte[idx] = (n < 8) ? f2bf(We2[k * 8 + n]) : (unsigned short)0;
    }
    if (idx < 128 * 8) {
        int k = idx >> 3, j = idx & 7;
        int h = j & 3;
        const float* av = (j < 4) ? as_ : ad_;
        float sum = 0.f;
        for (int c = 0; c < 64; c++) sum += W1[k * 256 + h * 64 + c] * av[h * 64 + c];
        watt[k * 8 + j] = sum;
    }
}

// ---------------- attention scalars from x (+ bf16 copy of x): wave per node ----------------
__global__ __launch_bounds__(256) void asad_kernel(const float* __restrict__ x,
                                                   const float* __restrict__ watt,
                                                   float4* __restrict__ as4,
                                                   float4* __restrict__ ad4,
                                                   unsigned* __restrict__ xb) {
    int wid = (blockIdx.x * blockDim.x + threadIdx.x) >> 6;
    int lane = threadIdx.x & 63;
    if (wid >= N_NODES) return;
    float2 xv = *reinterpret_cast<const float2*>(&x[(size_t)wid * 128 + lane * 2]);
    xb[(size_t)wid * 64 + lane] = pack2bf(xv.x, xv.y);
    float p[8];
    const float* w0 = &watt[(2 * lane) * 8];
    const float* w1 = &watt[(2 * lane + 1) * 8];
#pragma unroll
    for (int j = 0; j < 8; j++) p[j] = fmaf(xv.x, w0[j], xv.y * w1[j]);
#pragma unroll
    for (int off = 32; off; off >>= 1)
#pragma unroll
        for (int j = 0; j < 8; j++) p[j] += __shfl_xor(p[j], off, 64);
    if (lane == 0) {
        as4[wid] = make_float4(p[0], p[1], p[2], p[3]);
        ad4[wid] = make_float4(p[4], p[5], p[6], p[7]);
    }
}

// ---------------- conv1 accumulate: wave/node; packed f32 math (v_pk_fma_f32) ----------------
__global__ __launch_bounds__(256) void agg4x_acc_kernel(const unsigned* __restrict__ xb,
                                                        const float4* __restrict__ as4,
                                                        const float4* __restrict__ ad4,
                                                        const int* __restrict__ row_start,
                                                        const uint4* __restrict__ edges,
                                                        unsigned* __restrict__ xaggb) {
    int wid = (blockIdx.x * blockDim.x + threadIdx.x) >> 6;
    int lane = threadIdx.x & 63;
    if (wid >= N_NODES) return;
    int beg = __builtin_amdgcn_readfirstlane(row_start[wid]);
    int end = __builtin_amdgcn_readfirstlane(row_start[wid + 1]);
    float4 adn = ad4[wid];
    float4 e_self = exp4(lrelu4(as4[wid] + adn));
    f32x2 den01 = {e_self.x, e_self.y};
    f32x2 den23 = {e_self.z, e_self.w};
    f32x2 xv = bf2v2(xb[(size_t)wid * 64 + lane]);
    f32x2 acc0 = e_self.x * xv;
    f32x2 acc1 = e_self.y * xv;
    f32x2 acc2 = e_self.z * xv;
    f32x2 acc3 = e_self.w * xv;

#define EDGE_ACC(rec, vu)                                                     \
    {                                                                         \
        f32x2 a01 = unpack2hv((rec).z);                                       \
        f32x2 a23 = unpack2hv((rec).w);                                       \
        f32x2 vv = bf2v2(vu);                                                 \
        acc0 += a01.x * vv;                                                   \
        acc1 += a01.y * vv;                                                   \
        acc2 += a23.x * vv;                                                   \
        acc3 += a23.y * vv;                                                   \
        den01 += a01;                                                         \
        den23 += a23;                                                         \
    }

    int j = beg;
    for (; j + 3 < end; j += 4) {
        uint4 r0 = edges[j], r1 = edges[j + 1], r2 = edges[j + 2], r3 = edges[j + 3];
        unsigned v0 = xb[(size_t)(r0.x & 0xffff) * 64 + lane];
        unsigned v1 = xb[(size_t)(r1.x & 0xffff) * 64 + lane];
        unsigned v2 = xb[(size_t)(r2.x & 0xffff) * 64 + lane];
        unsigned v3 = xb[(size_t)(r3.x & 0xffff) * 64 + lane];
        EDGE_ACC(r0, v0);
        EDGE_ACC(r1, v1);
        EDGE_ACC(r2, v2);
        EDGE_ACC(r3, v3);
    }
    for (; j < end; j++) {
        uint4 r = edges[j];
        unsigned v = xb[(size_t)(r.x & 0xffff) * 64 + lane];
        EDGE_ACC(r, v);
    }
#undef EDGE_ACC
    float i0 = 1.f / (den01.x + 1e-16f);
    float i1 = 1.f / (den01.y + 1e-16f);
    float i2 = 1.f / (den23.x + 1e-16f);
    float i3 = 1.f / (den23.y + 1e-16f);
    size_t base = (size_t)wid * 64 + lane;
    xaggb[0 * PLANEU + base] = pack2bf(acc0.x * i0, acc0.y * i0);
    xaggb[1 * PLANEU + base] = pack2bf(acc1.x * i1, acc1.y * i1);
    xaggb[2 * PLANEU + base] = pack2bf(acc2.x * i2, acc2.y * i2);
    xaggb[3 * PLANEU + base] = pack2bf(acc3.x * i3, acc3.y * i3);
}

// ================= MFMA GEMMs (16x16x32 bf16, LDS-free) =================

template <int K>
__global__ __launch_bounds__(256) void mfma_gemm1_kernel(const unsigned short* __restrict__ A,
                                                         int lda, long aPlane,
                                                         const unsigned short* __restrict__ Bt,
                                                         const float* __restrict__ bias,
                                                         unsigned short* __restrict__ C, int ldc,
                                                         int M) {
    int tid = threadIdx.x;
    int w = tid >> 6, l = tid & 63;
    int bcol = blockIdx.y * 64;
    A += (size_t)blockIdx.y * aPlane;
    int row_a = blockIdx.x * 64 + w * 16 + (l & 15);
    int kq = (l >> 4) * 8;
    bool aval = row_a < M;
    const unsigned short* Arow = A + (size_t)row_a * lda;
    f32x4 acc[4] = {};
#pragma unroll
    for (int kb = 0; kb < K / 32; kb++) {
        int k0 = kb * 32 + kq;
        bf16x8 a = {};
        if (aval) a = *reinterpret_cast<const bf16x8*>(&Arow[k0]);
#pragma unroll
        for (int nb = 0; nb < 4; nb++) {
            bf16x8 b = *reinterpret_cast<const bf16x8*>(
                &Bt[(size_t)(bcol + nb * 16 + (l & 15)) * K + k0]);
            acc[nb] = __builtin_amdgcn_mfma_f32_16x16x32_bf16(a, b, acc[nb], 0, 0, 0);
        }
    }
    int orow = blockIdx.x * 64 + w * 16 + (l >> 4) * 4;
#pragma unroll
    for (int nb = 0; nb < 4; nb++) {
        int col = bcol + nb * 16 + (l & 15);
        float bb = bias[col];
#pragma unroll
        for (int r = 0; r < 4; r++) {
            int row = orow + r;
            if (row < M) C[(size_t)row * ldc + col] = f2bf(fmaxf(acc[nb][r] + bb, 0.f));
        }
    }
}

__global__ __launch_bounds__(256) void mfma_gemm2_kernel(const unsigned short* __restrict__ A,
                                                         const unsigned short* __restrict__ Bt,
                                                         const float* __restrict__ att_src,
                                                         const float* __restrict__ att_dst,
                                                         unsigned short* __restrict__ h2b,
                                                         float* __restrict__ as_,
                                                         float* __restrict__ ad_, int M) {
    int tid = threadIdx.x;
    int w = tid >> 6, l = tid & 63;
    int row_a = blockIdx.x * 64 + w * 16 + (l & 15);
    int kq = (l >> 4) * 8;
    bool aval = row_a < M;
    const unsigned short* Arow = A + (size_t)row_a * 256;
    f32x4 acc[4] = {};
#pragma unroll
    for (int kb = 0; kb < 8; kb++) {
        int k0 = kb * 32 + kq;
        bf16x8 a = {};
        if (aval) a = *reinterpret_cast<const bf16x8*>(&Arow[k0]);
#pragma unroll
        for (int nb = 0; nb < 4; nb++) {
            bf16x8 b = *reinterpret_cast<const bf16x8*>(
                &Bt[(size_t)(nb * 16 + (l & 15)) * 256 + k0]);
            acc[nb] = __builtin_amdgcn_mfma_f32_16x16x32_bf16(a, b, acc[nb], 0, 0, 0);
        }
    }
    int orow = blockIdx.x * 64 + w * 16 + (l >> 4) * 4;
    float ps[4] = {}, pd[4] = {};
#pragma unroll
    for (int nb = 0; nb < 4; nb++) {
        int col = nb * 16 + (l & 15);
        float s = att_src[col], dd = att_dst[col];
#pragma unroll
        for (int r = 0; r < 4; r++) {
            float v = acc[nb][r];
            ps[r] = fmaf(v, s, ps[r]);
            pd[r] = fmaf(v, dd, pd[r]);
            int row = orow + r;
            if (row < M) h2b[(size_t)row * 64 + col] = f2bf(v);
        }
    }
#pragma unroll
    for (int off = 1; off <= 8; off <<= 1)
#pragma unroll
        for (int r = 0; r < 4; r++) {
            ps[r] += __shfl_xor(ps[r], off, 64);
            pd[r] += __shfl_xor(pd[r], off, 64);
        }
    if ((l & 15) == 0) {
#pragma unroll
        for (int r = 0; r < 4; r++) {
            int row = orow + r;
            if (row < M) { as_[row] = ps[r]; ad_[row] = pd[r]; }
        }
    }
}

__global__ __launch_bounds__(256) void mfma_gemm_decode_kernel(const unsigned short* __restrict__ zb,
                                                               const unsigned short* __restrict__ Btd,
                                                               const float* __restrict__ bn,
                                                               float* __restrict__ recon_x,
                                                               unsigned short* __restrict__ PQb,
                                                               int M) {
    int tid = threadIdx.x;
    int w = tid >> 6, l = tid & 63;
    int bcol = blockIdx.y * 64;
    int row_a = blockIdx.x * 64 + w * 16 + (l & 15);
    int kq = (l >> 4) * 8;
    bool aval = row_a < M;
    const unsigned short* Arow = zb + (size_t)row_a * 64;
    f32x4 acc[4] = {};
#pragma unroll
    for (int kb = 0; kb < 2; kb++) {
        int k0 = kb * 32 + kq;
        bf16x8 a = {};
        if (aval) a = *reinterpret_cast<const bf16x8*>(&Arow[k0]);
#pragma unroll
        for (int nb = 0; nb < 4; nb++) {
            bf16x8 b = *reinterpret_cast<const bf16x8*>(
                &Btd[(size_t)(bcol + nb * 16 + (l & 15)) * 64 + k0]);
            acc[nb] = __builtin_amdgcn_mfma_f32_16x16x32_bf16(a, b, acc[nb], 0, 0, 0);
        }
    }
    int orow = blockIdx.x * 64 + w * 16 + (l >> 4) * 4;
#pragma unroll
    for (int nb = 0; nb < 4; nb++) {
        int col = bcol + nb * 16 + (l & 15);
        if (col < 128) {
            float bb = bn[col];
#pragma unroll
            for (int r = 0; r < 4; r++) {
                int row = orow + r;
                if (row < M) recon_x[(size_t)row * 128 + col] = acc[nb][r] + bb;
            }
        } else {
#pragma unroll
            for (int r = 0; r < 4; r++) {
                int row = orow + r;
                if (row < M) PQb[(size_t)row * 128 + (col - 128)] = f2bf(acc[nb][r]);
            }
        }
    }
}

// ---------------- conv2 per-edge alpha: packed {alpha_bits, src} records ----------------
__global__ void alpha1_kernel(const uint4* __restrict__ edges,
                              const float* __restrict__ as_, const float* __restrict__ ad_,
                              uint2* __restrict__ av) {
    int p = blockIdx.x * blockDim.x + threadIdx.x;
    if (p < N_EDGES) {
        unsigned w0 = edges[p].x;
        int s = w0 & 0xffff;
        float a = __expf(lrelu(as_[s] + ad_[w0 >> 16]));
        av[p] = make_uint2(__float_as_uint(a), (unsigned)s);
    }
}

// ---------------- conv2 accumulate: 4 edge-slots x 16 lanes, 4 edges/iter ----------------
__global__ __launch_bounds__(256) void agg1_acc_kernel(const uint2* __restrict__ h2b2,
                                                       const float* __restrict__ as_,
                                                       const float* __restrict__ ad_,
                                                       const int* __restrict__ row_start,
                                                       const uint2* __restrict__ av,
                                                       const float* __restrict__ bias,
                                                       unsigned* __restrict__ zb) {
    int wid = (blockIdx.x * blockDim.x + threadIdx.x) >> 6;
    int lane = threadIdx.x & 63;
    if (wid >= N_NODES) return;
    int g = lane >> 4;        // edge slot 0..3
    int c16 = lane & 15;      // channel quad -> channels [c16*4, c16*4+4)
    int beg = __builtin_amdgcn_readfirstlane(row_start[wid]);
    int end = __builtin_amdgcn_readfirstlane(row_start[wid + 1]);
    float adn = ad_[wid];
    float e_self = __expf(lrelu(as_[wid] + adn));
    float den = (g == 0) ? e_self : 0.f;
    uint2 hv = h2b2[(size_t)wid * 16 + c16];
    float2 h01 = bf2f2(hv.x), h23 = bf2f2(hv.y);
    float4 acc = (g == 0) ? make_float4(e_self * h01.x, e_self * h01.y,
                                        e_self * h23.x, e_self * h23.y)
                          : make_float4(0.f, 0.f, 0.f, 0.f);
    for (int j = beg + g; j < end; j += 4) {
        uint2 rec = av[j];
        float e = __uint_as_float(rec.x);
        uint2 v = h2b2[(size_t)rec.y * 16 + c16];
        float2 v01 = bf2f2(v.x), v23 = bf2f2(v.y);
        acc.x = fmaf(e, v01.x, acc.x);
        acc.y = fmaf(e, v01.y, acc.y);
        acc.z = fmaf(e, v23.x, acc.z);
        acc.w = fmaf(e, v23.y, acc.w);
        den += e;
    }
#pragma unroll
    for (int off = 16; off <= 32; off <<= 1) {
        den += __shfl_xor(den, off, 64);
        acc.x += __shfl_xor(acc.x, off, 64);
        acc.y += __shfl_xor(acc.y, off, 64);
        acc.z += __shfl_xor(acc.z, off, 64);
        acc.w += __shfl_xor(acc.w, off, 64);
    }
    if (g == 0) {
        float inv = 1.f / (den + 1e-16f);
        const float4 bb = *reinterpret_cast<const float4*>(&bias[c16 * 4]);
        uint2 o;
        o.x = pack2bf(acc.x * inv + bb.x, acc.y * inv + bb.y);
        o.y = pack2bf(acc.z * inv + bb.z, acc.w * inv + bb.w);
        *reinterpret_cast<uint2*>(&zb[(size_t)wid * 32 + c16 * 2]) = o;
    }
}

// ---------------- MFMA edge decode: 16 edges/wave, 16B records ----------------
#define ED_BLOCKS 2048
__device__ __forceinline__ bf16x8 make_t(uint4 up, uint4 uq, float4 ba, float4 bb) {
    float2 p0 = bf2f2(up.x), p1 = bf2f2(up.y), p2 = bf2f2(up.z), p3 = bf2f2(up.w);
    float2 q0 = bf2f2(uq.x), q1 = bf2f2(uq.y), q2 = bf2f2(uq.z), q3 = bf2f2(uq.w);
    unsigned r0 = pack2bf(fmaxf(p0.x + q0.x + ba.x, 0.f), fmaxf(p0.y + q0.y + ba.y, 0.f));
    unsigned r1 = pack2bf(fmaxf(p1.x + q1.x + ba.z, 0.f), fmaxf(p1.y + q1.y + ba.w, 0.f));
    unsigned r2 = pack2bf(fmaxf(p2.x + q2.x + bb.x, 0.f), fmaxf(p2.y + q2.y + bb.y, 0.f));
    unsigned r3 = pack2bf(fmaxf(p3.x + q3.x + bb.z, 0.f), fmaxf(p3.y + q3.y + bb.w, 0.f));
    union { uint4 u; bf16x8 v; } c;
    c.u = make_uint4(r0, r1, r2, r3);
    return c.v;
}

__global__ __launch_bounds__(256) void mfma_edge_decode_kernel(const unsigned short* __restrict__ PQb,
                                                               const uint4* __restrict__ edges,
                                                               const float* __restrict__ be1,
                                                               const unsigned short* __restrict__ Bte,
                                                               const float* __restrict__ be2,
                                                               float* __restrict__ out) {
    int tid = threadIdx.x;
    int l = tid & 63;
    int col = l & 15;
    int kq = (l >> 4) * 8;
    bf16x8 b0 = *reinterpret_cast<const bf16x8*>(&Bte[col * 64 + kq]);
    bf16x8 b1 = *reinterpret_cast<const bf16x8*>(&Bte[col * 64 + 32 + kq]);
    float4 ba0 = *reinterpret_cast<const float4*>(&be1[kq]);
    float4 bb0 = *reinterpret_cast<const float4*>(&be1[kq + 4]);
    float4 ba1 = *reinterpret_cast<const float4*>(&be1[32 + kq]);
    float4 bb1 = *reinterpret_cast<const float4*>(&be1[32 + kq + 4]);
    float bout = (col < 8) ? be2[col] : 0.f;
    int rbase = (l >> 4) * 4;

    int wgid = (blockIdx.x * blockDim.x + tid) >> 6;
    const int nwaves = ED_BLOCKS * 4;
    const int ngroups = N_EDGES / 16;
    for (int g = wgid; g < ngroups; g += nwaves) {
        int base = g * 16;
        unsigned ex = edges[base + col].x;
        int s = ex & 0xffff, d = ex >> 16;
        const unsigned short* Pr = &PQb[(size_t)s * 128];
        const unsigned short* Qr = &PQb[(size_t)d * 128 + 64];
        uint4 up0 = *reinterpret_cast<const uint4*>(&Pr[kq]);
        uint4 uq0 = *reinterpret_cast<const uint4*>(&Qr[kq]);
        uint4 up1 = *reinterpret_cast<const uint4*>(&Pr[32 + kq]);
        uint4 uq1 = *reinterpret_cast<const uint4*>(&Qr[32 + kq]);
        bf16x8 a0 = make_t(up0, uq0, ba0, bb0);
        bf16x8 a1 = make_t(up1, uq1, ba1, bb1);
        f32x4 acc = {};
        acc = __builtin_amdgcn_mfma_f32_16x16x32_bf16(a0, b0, acc, 0, 0, 0);
        acc = __builtin_amdgcn_mfma_f32_16x16x32_bf16(a1, b1, acc, 0, 0, 0);
        if (col < 8) {
#pragma unroll
            for (int r = 0; r < 4; r++) {
                int o = edges[base + rbase + r].y;
                out[(size_t)o * 8 + col] = acc[r] + bout;
            }
        }
    }
}

extern "C" void kernel_launch(void* const* d_in, const int* in_sizes, int n_in,
                              void* d_out, int out_size, void* d_ws, size_t ws_size,
                              hipStream_t stream) {
    const float* x        = (const float*)d_in[0];
    const int*   ei       = (const int*)d_in[1];
    const float* W1       = (const float*)d_in[2];
    const float* att_src1 = (const float*)d_in[3];
    const float* att_dst1 = (const float*)d_in[4];
    const float* b1       = (const float*)d_in[5];
    const float* W2       = (const float*)d_in[6];
    const float* att_src2 = (const float*)d_in[7];
    const float* att_dst2 = (const float*)d_in[8];
    const float* b2       = (const float*)d_in[9];
    const float* Wn       = (const float*)d_in[10];
    const float* bn       = (const float*)d_in[11];
    const float* We1      = (const float*)d_in[12];
    const float* be1      = (const float*)d_in[13];
    const float* We2      = (const float*)d_in[14];
    const float* be2      = (const float*)d_in[15];

    char* ws = (char*)d_ws;
    size_t off = 0;
    auto alloc = [&](size_t bytes) {
        void* p = ws + off;
        off += (bytes + 255) & ~(size_t)255;
        return p;
    };
    int*   hist      = (int*)alloc((size_t)NABLK * NBUCKET * 4);
    int*   bbase     = (int*)alloc((size_t)(NBUCKET + 1) * 4);
    int*   row_start = (int*)alloc((size_t)(N_NODES + 1) * 4);
    uint2* coarse    = (uint2*)alloc((size_t)N_EDGES * 8);
    uint4* edges     = (uint4*)alloc((size_t)N_EDGES * 16);
    float* watt      = (float*)alloc((size_t)128 * 8 * 4);
    float* as1       = (float*)alloc((size_t)N_NODES * 4 * 4);
    float* ad1       = (float*)alloc((size_t)N_NODES * 4 * 4);
    unsigned* xb     = (unsigned*)alloc((size_t)N_NODES * 64 * 4);
    unsigned* xaggb  = (unsigned*)alloc((size_t)4 * PLANEU * 4);
    unsigned short* houtb = (unsigned short*)alloc((size_t)N_NODES * 256 * 2);
    unsigned* h2b    = (unsigned*)alloc((size_t)N_NODES * 32 * 4);
    float* as2       = (float*)alloc((size_t)N_NODES * 4);
    float* ad2       = (float*)alloc((size_t)N_NODES * 4);
    uint2* av        = (uint2*)alloc((size_t)N_EDGES * 8);
    unsigned* zb     = (unsigned*)alloc((size_t)N_NODES * 32 * 4);
    unsigned short* PQb = (unsigned short*)alloc((size_t)N_NODES * 128 * 2);
    unsigned short* Bt1 = (unsigned short*)alloc((size_t)256 * 128 * 2);
    unsigned short* Bt2 = (unsigned short*)alloc((size_t)64 * 256 * 2);
    unsigned short* Btd = (unsigned short*)alloc((size_t)256 * 64 * 2);
    unsigned short* Bte = (unsigned short*)alloc((size_t)16 * 64 * 2);

    float* recon_x = (float*)d_out;
    float* recon_e = (float*)d_out + (size_t)N_NODES * F_IN;

    // CSR build: atomic-free histogram/scan/scatter + fused-alpha fine pass
    bucket_count_kernel<<<NABLK, 256, 0, stream>>>(ei, hist);
    scan_buckets_kernel<<<1, 256, 0, stream>>>(hist, bbase, row_start);
    wts_kernel<<<128, 256, 0, stream>>>(W1, W2, Wn, We1, We2, att_src1, att_dst1,
                                        watt, Bt1, Bt2, Btd, Bte);
    asad_kernel<<<(N_NODES * 64 + 255) / 256, 256, 0, stream>>>(x, watt, (float4*)as1,
                                                                (float4*)ad1, xb);
    coarse_scatter_kernel<<<NABLK, 256, 0, stream>>>(ei, hist, coarse);
    fine_pass_kernel<<<NBUCKET, 256, 0, stream>>>(coarse, bbase, (const float4*)as1,
                                                  (const float4*)ad1, edges, row_start);

    // conv1 accumulate + per-head MFMA GEMM applies W1 (bf16 out)
    agg4x_acc_kernel<<<(N_NODES * 64 + 255) / 256, 256, 0, stream>>>(
        xb, (const float4*)as1, (const float4*)ad1, row_start, edges, xaggb);
    dim3 gc1((N_NODES + 63) / 64, 4);
    mfma_gemm1_kernel<128><<<gc1, 256, 0, stream>>>(
        (const unsigned short*)xaggb, 128, (long)PLANE, Bt1, b1, houtb, 256, N_NODES);

    // conv2: MFMA GEMM with fused att-scalar epilogue, then alpha + accumulate
    mfma_gemm2_kernel<<<(N_NODES + 63) / 64, 256, 0, stream>>>(
        houtb, Bt2, att_src2, att_dst2, (unsigned short*)h2b, as2, ad2, N_NODES);
    alpha1_kernel<<<(N_EDGES + 255) / 256, 256, 0, stream>>>(edges, as2, ad2, av);
    agg1_acc_kernel<<<(N_NODES * 64 + 255) / 256, 256, 0, stream>>>(
        (const uint2*)h2b, as2, ad2, row_start, av, b2, zb);

    // fused decode MFMA GEMM: recon_x (fp32) + PQ (bf16) in one pass over zb
    dim3 gdec((N_NODES + 63) / 64, 4);
    mfma_gemm_decode_kernel<<<gdec, 256, 0, stream>>>(
        (const unsigned short*)zb, Btd, bn, recon_x, PQb, N_NODES);

    // MFMA edge decode (CSR order, 16B records)
    mfma_edge_decode_kernel<<<ED_BLOCKS, 256, 0, stream>>>(PQb, edges, be1, Bte, be2, recon_e);
}